// Round 1
// baseline (805.119 us; speedup 1.0000x reference)
//
#include <hip/hip_runtime.h>

typedef unsigned short u16;
typedef short s8v __attribute__((ext_vector_type(8)));   // 8 x bf16 bits (4 VGPRs)
typedef float f32x4 __attribute__((ext_vector_type(4)));

#define MFMA16(a, b, c) __builtin_amdgcn_mfma_f32_16x16x32_bf16((a), (b), (c), 0, 0, 0)
#define GLDS16(gp, lp)                                                         \
  __builtin_amdgcn_global_load_lds(                                            \
      (const __attribute__((address_space(1))) void*)(gp),                     \
      (__attribute__((address_space(3))) void*)(lp), 16, 0, 0)

__device__ __forceinline__ float bf2f(u16 u) {
  unsigned int i = ((unsigned int)u) << 16;
  float f;
  __builtin_memcpy(&f, &i, 4);
  return f;
}
__device__ __forceinline__ u16 f2bf(float f) {
  unsigned int u;
  __builtin_memcpy(&u, &f, 4);
  unsigned int r = (u + 0x7FFFu + ((u >> 16) & 1u)) >> 16;  // RNE
  return (u16)r;
}

// ---------------- f32 -> bf16 convert (activations) -------------------------
__global__ __launch_bounds__(256) void cvt_f32_bf16(const float* __restrict__ s,
                                                    u16* __restrict__ d, long n) {
  long i = ((long)blockIdx.x * 256 + threadIdx.x) * 4;
  if (i + 3 < n) {
    float4 v = *(const float4*)(s + i);
    ushort4 o;
    o.x = f2bf(v.x); o.y = f2bf(v.y); o.z = f2bf(v.z); o.w = f2bf(v.w);
    *(ushort4*)(d + i) = o;
  }
}

// ------- batched 2048x2048 transpose + convert (f32 K-major -> bf16 N-major)
// All 6 weight matrices in one launch (blockIdx.z selects); removes 5 launch
// boundaries and the false w0/w1 serialization against the GEMMs.
struct TransposeBatch {
  const float* src[6];
  u16* dst[6];
};

__global__ __launch_bounds__(256) void transpose2048_batch(TransposeBatch p) {
  const float* __restrict__ W = p.src[blockIdx.z];
  u16* __restrict__ Wt = p.dst[blockIdx.z];
  __shared__ u16 t[64][65];
  int c0 = blockIdx.x * 64, r0 = blockIdx.y * 64;
  int x = threadIdx.x & 63, y = threadIdx.x >> 6;
  for (int yy = y; yy < 64; yy += 4)
    t[yy][x] = f2bf(W[(long)(r0 + yy) * 2048 + c0 + x]);
  __syncthreads();
  for (int yy = y; yy < 64; yy += 4)
    Wt[(long)(c0 + yy) * 2048 + r0 + x] = t[x][yy];
}

// ---------------- GEMM: Y[M x N] = A[M x 2048] * Bt^T + bias ----------------
// DUAL=1: n in [2048,4096) goes to Yv2/bias2 (two fused output tensors).
template <int OUTF, int DUAL>
__global__ __launch_bounds__(256, 2) void gemm_bias_bt(
    const u16* __restrict__ A, const u16* __restrict__ Bt,
    const float* __restrict__ bias, const float* __restrict__ bias2,
    void* __restrict__ Yv, void* __restrict__ Yv2, int M, int rpb, int bstride,
    int roff) {
  __shared__ u16 smA[128 * 32];
  __shared__ u16 smB[128 * 32];
  const int tid = threadIdx.x;
  const int wave = tid >> 6, lane = tid & 63;
  const int lo = lane & 15, qd = lane >> 4;
  const int m0 = blockIdx.x * 128, n0 = blockIdx.y * 128;
  const int wm = (wave & 1) * 64, wn = (wave >> 1) * 64;

  const u16* aG[2];
  const u16* bG[2];
  u16* aL[2];
  u16* bL[2];
#pragma unroll
  for (int r = 0; r < 2; ++r) {
    int c = (wave * 2 + r) * 64 + lane;  // 16B chunk id, c = row*4 + seg
    int row = c >> 2, seg = c & 3;
    int gr = m0 + row;
    if (gr > M - 1) gr = M - 1;
    long grow = (long)(gr / rpb) * bstride + roff + (gr % rpb);
    aG[r] = A + grow * 2048 + seg * 8;
    bG[r] = Bt + (long)(n0 + row) * 2048 + seg * 8;
    aL[r] = smA + (wave * 2 + r) * 512;  // wave-uniform LDS base
    bL[r] = smB + (wave * 2 + r) * 512;
  }

  f32x4 acc[4][4] = {};
  for (int k0 = 0; k0 < 2048; k0 += 32) {
    GLDS16(aG[0] + k0, aL[0]);
    GLDS16(aG[1] + k0, aL[1]);
    GLDS16(bG[0] + k0, bL[0]);
    GLDS16(bG[1] + k0, bL[1]);
    __syncthreads();
    s8v af[4], bf[4];
#pragma unroll
    for (int i = 0; i < 4; i++)
      af[i] = *(const s8v*)(smA + (wm + i * 16 + lo) * 32 + qd * 8);
#pragma unroll
    for (int i = 0; i < 4; i++)
      bf[i] = *(const s8v*)(smB + (wn + i * 16 + lo) * 32 + qd * 8);
#pragma unroll
    for (int i = 0; i < 4; i++)
#pragma unroll
      for (int j = 0; j < 4; j++) acc[i][j] = MFMA16(af[i], bf[j], acc[i][j]);
    __syncthreads();
  }
#pragma unroll
  for (int j = 0; j < 4; j++) {
    int nf = n0 + wn + j * 16 + lo;
    const float* bp = bias;
    void* yp = Yv;
    int n = nf;
    if (DUAL && nf >= 2048) {
      bp = bias2;
      yp = Yv2;
      n = nf - 2048;
    }
    float bv = bp[n];
#pragma unroll
    for (int i = 0; i < 4; i++) {
      int mb = m0 + wm + i * 16 + qd * 4;
#pragma unroll
      for (int r = 0; r < 4; r++) {
        int m = mb + r;
        if (m < M) {
          float val = acc[i][j][r] + bv;
          if (OUTF)
            ((float*)yp)[(long)m * 2048 + n] = val;
          else
            ((u16*)yp)[(long)m * 2048 + n] = f2bf(val);
        }
      }
    }
  }
}

// ---------------- RMS norm over rows of 2048 (bf16 in place, f32 scale) -----
__global__ __launch_bounds__(256) void rmsnorm_rows(u16* __restrict__ X,
                                                    const float* __restrict__ sc) {
  long row = blockIdx.x;
  u16* xr = X + row * 2048;
  int tid = threadIdx.x;
  s8v v = *(const s8v*)(xr + tid * 8);
  float f[8], ss = 0.f;
#pragma unroll
  for (int j = 0; j < 8; j++) {
    f[j] = bf2f((u16)v[j]);
    ss += f[j] * f[j];
  }
  for (int o = 1; o < 64; o <<= 1) ss += __shfl_xor(ss, o);
  __shared__ float wsum[4];
  if ((tid & 63) == 0) wsum[tid >> 6] = ss;
  __syncthreads();
  float tot = wsum[0] + wsum[1] + wsum[2] + wsum[3];
  float rs = rsqrtf(tot * (1.f / 2048.f) + 1e-6f);
  float4 s0 = *(const float4*)(sc + tid * 8);
  float4 s1 = *(const float4*)(sc + tid * 8 + 4);
  float scv[8] = {s0.x, s0.y, s0.z, s0.w, s1.x, s1.y, s1.z, s1.w};
  s8v o8;
#pragma unroll
  for (int j = 0; j < 8; j++) o8[j] = (short)f2bf(f[j] * rs * scv[j]);
  *(s8v*)(xr + tid * 8) = o8;
}

// ---------------- V repack: V[b][l][h][d] -> VT[b][h][d][l] (zero-pad l) ----
__global__ __launch_bounds__(256) void repack_vt(const u16* __restrict__ V,
                                                 u16* __restrict__ VT, int L,
                                                 int Lpad) {
  int bh = blockIdx.z;  // b*16 + h
  int b = bh >> 4, h = bh & 15;
  int l0 = blockIdx.x * 64, d0 = blockIdx.y * 64;
  __shared__ u16 t[64][65];
  int x = threadIdx.x & 63, y = threadIdx.x >> 6;
  for (int yy = y; yy < 64; yy += 4) {
    int l = l0 + yy;
    u16 val = 0;
    if (l < L) val = V[((long)(b * L + l)) * 2048 + h * 128 + d0 + x];
    t[yy][x] = val;
  }
  __syncthreads();
  for (int yy = y; yy < 64; yy += 4) {
    int d = d0 + yy;
    int l = l0 + x;
    if (l < Lpad) VT[((long)bh * 128 + d) * Lpad + l] = t[x][yy];
  }
}

// ---------------- single-phase cross-attention ------------------------------
// 32 queries/wave. Fixed-offset softmax: p = exp(s*sc - 12) (exact; per-lane
// denominator reduced once at the end). No block barriers; wave-private,
// parity-double-buffered P slice in LDS (same-buffer aliasing keeps the
// compiler from reordering the ds store->read; it emits the lgkmcnt).
// Rolled loop + unroll 2: small scheduling window -> no spill (round-4
// full-unroll + 128-reg cap spilled oacc: WRITE_SIZE 33->788 MB).
// launch_bounds(256,3): cap 170 regs total (oacc 64 AGPR + aq 16 + ~75 live)
// -> 3 waves/SIMD instead of round-3's 2 (172 total regs).
// T5 (m191): setprio(1) around both MFMA clusters — waves here are
// independent (no block barriers), the regime where setprio measured +4-7%.
template <int ADD, int L, int LPAD, int NT>
__global__ __launch_bounds__(256, 3) void cross_attn(
    const u16* __restrict__ Q, const u16* __restrict__ K,
    const u16* __restrict__ VT, u16* __restrict__ O) {
  const int tid = threadIdx.x, wave = tid >> 6, lane = tid & 63;
  const int lo = lane & 15, qd = lane >> 4;
  const int h = blockIdx.y, b = blockIdx.z;
  const int q0 = blockIdx.x * 128 + wave * 32;
  __shared__ u16 pls[4][2][1280];  // [wave][parity][32 q x stride 40]

  const u16* Kb = K + ((long)b * L) * 2048 + h * 128;
  const u16* VTb = VT + ((long)(b * 16 + h)) * 128 * LPAD;

  s8v aq[2][4];
#pragma unroll
  for (int qf = 0; qf < 2; ++qf) {
    const u16* qp =
        Q + ((long)(b * 4096 + q0 + qf * 16 + lo)) * 2048 + h * 128 + qd * 8;
#pragma unroll
    for (int ds = 0; ds < 4; ++ds) aq[qf][ds] = *(const s8v*)(qp + ds * 32);
  }

  const float SC = 0.08838834764831845f;  // 1/sqrt(128)
  f32x4 oacc[2][8] = {};
  float lsum[2][4] = {};

#pragma unroll 2
  for (int kt = 0; kt < NT; ++kt) {
    // ---- K fragments (q-independent) ----
    s8v bk[2][4];
#pragma unroll
    for (int nf = 0; nf < 2; ++nf) {
      int key = kt * 32 + nf * 16 + lo;
      int keyc = key < L ? key : L - 1;
      const u16* kp = Kb + (long)keyc * 2048 + qd * 8;
#pragma unroll
      for (int ds = 0; ds < 4; ++ds) bk[nf][ds] = *(const s8v*)(kp + ds * 32);
    }
    // ---- QK^T ----
    f32x4 sacc[2][2] = {};
    __builtin_amdgcn_s_setprio(1);
#pragma unroll
    for (int qf = 0; qf < 2; ++qf)
#pragma unroll
      for (int nf = 0; nf < 2; ++nf)
#pragma unroll
        for (int ds = 0; ds < 4; ++ds)
          sacc[qf][nf] = MFMA16(aq[qf][ds], bk[nf][ds], sacc[qf][nf]);
    __builtin_amdgcn_s_setprio(0);
    // ---- exp (fixed offset), accumulate denominator, P -> LDS ----
    u16* pw = pls[wave][kt & 1];
#pragma unroll
    for (int qf = 0; qf < 2; ++qf)
#pragma unroll
      for (int nf = 0; nf < 2; ++nf) {
        int key = kt * 32 + nf * 16 + lo;
        bool msk = key >= L;
#pragma unroll
        for (int r = 0; r < 4; ++r) {
          float s = fminf(fmaf(sacc[qf][nf][r], SC, -12.f), 50.f);
          float p = msk ? 0.f : __expf(s);
          lsum[qf][r] += p;
          pw[(qf * 16 + qd * 4 + r) * 40 + nf * 16 + lo] = f2bf(p);
        }
      }
    s8v pa[2];
#pragma unroll
    for (int qf = 0; qf < 2; ++qf)
      pa[qf] = *(const s8v*)(pw + (qf * 16 + lo) * 40 + qd * 8);
    // ---- P * V ----
    const u16* vp = VTb + (long)lo * LPAD + kt * 32 + qd * 8;
    __builtin_amdgcn_s_setprio(1);
#pragma unroll
    for (int df = 0; df < 8; ++df) {
      s8v bv = *(const s8v*)(vp + (long)df * 16 * LPAD);
      oacc[0][df] = MFMA16(pa[0], bv, oacc[0][df]);
      oacc[1][df] = MFMA16(pa[1], bv, oacc[1][df]);
    }
    __builtin_amdgcn_s_setprio(0);
  }
  // ---- denominator reduce (over the 16 key-lanes) + output ----
#pragma unroll
  for (int qf = 0; qf < 2; ++qf)
#pragma unroll
    for (int r = 0; r < 4; ++r) {
      float l = lsum[qf][r];
      for (int o = 1; o < 16; o <<= 1) l += __shfl_xor(l, o);
      lsum[qf][r] = 1.f / l;
    }
  u16* op = O + ((long)(b * 4096 + q0)) * 2048 + h * 128;
#pragma unroll
  for (int qf = 0; qf < 2; ++qf)
#pragma unroll
    for (int df = 0; df < 8; ++df) {
      int d = df * 16 + lo;
#pragma unroll
      for (int r = 0; r < 4; ++r) {
        long idx = (long)(qf * 16 + qd * 4 + r) * 2048 + d;
        float val = oacc[qf][df][r] * lsum[qf][r];
        if (ADD) val += bf2f(op[idx]);
        op[idx] = f2bf(val);
      }
    }
}

extern "C" void kernel_launch(void* const* d_in, const int* in_sizes, int n_in,
                              void* d_out, int out_size, void* d_ws,
                              size_t ws_size, hipStream_t stream) {
  const float* x = (const float*)d_in[0];
  const float* ctx = (const float*)d_in[1];
  const float* q_w = (const float*)d_in[2];
  const float* q_b = (const float*)d_in[3];
  const float* k_w = (const float*)d_in[4];
  const float* k_b = (const float*)d_in[5];
  const float* v_w = (const float*)d_in[6];
  const float* v_b = (const float*)d_in[7];
  const float* ki_w = (const float*)d_in[8];
  const float* ki_b = (const float*)d_in[9];
  const float* vi_w = (const float*)d_in[10];
  const float* vi_b = (const float*)d_in[11];
  const float* o_w = (const float*)d_in[12];
  const float* o_b = (const float*)d_in[13];
  const float* nq_s = (const float*)d_in[14];
  const float* nkt_s = (const float*)d_in[15];
  const float* nki_s = (const float*)d_in[16];
  float* out = (float*)d_out;
  u16* ws = (u16*)d_ws;

  // workspace layout (u16 elements); total ~103 MB
  // q region (16,777,216) doubles as 4x weight-transpose staging before the
  // Q-GEMM overwrites it:  [k_w^T | v_w^T] dual-Bt pair at q+0,
  //                        [ki_w^T | vi_w^T] dual-Bt pair at q+8388608.
  u16* w0 = ws;                        //  4,194,304  (q_w^T)
  u16* w1 = ws + 4194304L;             //  4,194,304  (o_w^T)
  u16* q = ws + 8388608L;              // 16,777,216
  u16* attn = ws + 25165824L;          // 16,777,216
  u16* xb = attn;                      // alias (x bf16; dead before attn written)
  u16* vtxt = attn;                    // alias, 2,097,152 (dead before xb written)
  u16* vimg = attn + 2097152L;         // alias, 1,052,672
  u16* ktxt = ws + 41943040L;          //  2,097,152
  u16* kimg = ws + 44040192L;          //  1,052,672
  u16* vttxt = ws + 45092864L;         //  2,097,152 (32 x 128 x 512)
  u16* vtimg = ws + 47190016L;         //  1,179,648 (32 x 128 x 288)
  u16* ctxb = ws + 48369664L;          //  3,149,824

  dim3 tb(256);

  // Phase 0: context to bf16 + ALL weight transposes in one launch.
  cvt_f32_bf16<<<3076, tb, 0, stream>>>(ctx, ctxb, 3149824L);
  TransposeBatch tp;
  tp.src[0] = q_w;  tp.dst[0] = w0;
  tp.src[1] = o_w;  tp.dst[1] = w1;
  tp.src[2] = k_w;  tp.dst[2] = q;              // dual pair base (txt)
  tp.src[3] = v_w;  tp.dst[3] = q + 4194304L;
  tp.src[4] = ki_w; tp.dst[4] = q + 8388608L;   // dual pair base (img)
  tp.src[5] = vi_w; tp.dst[5] = q + 12582912L;
  transpose2048_batch<<<dim3(32, 32, 6), tb, 0, stream>>>(tp);

  // Phase 1: K|V projections (weights live in q region; q not written yet).
  gemm_bias_bt<0, 1><<<dim3(8, 32), tb, 0, stream>>>(
      ctxb, q, k_b, v_b, ktxt, vtxt, 1024, 512, 769, 257);
  gemm_bias_bt<0, 1><<<dim3(5, 32), tb, 0, stream>>>(
      ctxb, q + 8388608L, ki_b, vi_b, kimg, vimg, 514, 257, 769, 0);

  rmsnorm_rows<<<1024, tb, 0, stream>>>(ktxt, nkt_s);
  rmsnorm_rows<<<514, tb, 0, stream>>>(kimg, nki_s);
  repack_vt<<<dim3(8, 2, 32), tb, 0, stream>>>(vtxt, vttxt, 512, 512);
  repack_vt<<<dim3(5, 2, 32), tb, 0, stream>>>(vimg, vtimg, 257, 288);

  // Phase 2: x to bf16 (overwrites the now-repacked vtxt/vimg aliases),
  // then Q projection (output overwrites the now-dead ctx weight stages).
  cvt_f32_bf16<<<16384, tb, 0, stream>>>(x, xb, 16777216L);
  gemm_bias_bt<0, 0><<<dim3(64, 16), tb, 0, stream>>>(
      xb, w0, q_b, nullptr, q, nullptr, 8192, 4096, 4096, 0);
  rmsnorm_rows<<<8192, tb, 0, stream>>>(q, nq_s);

  // Phase 3: attention. txt writes attn (xb dead); img adds its result.
  cross_attn<0, 512, 512, 16><<<dim3(32, 16, 2), tb, 0, stream>>>(q, ktxt, vttxt, attn);
  cross_attn<1, 257, 288, 9><<<dim3(32, 16, 2), tb, 0, stream>>>(q, kimg, vtimg, attn);

  // Phase 4: output projection (o_w^T has been parked in w1 since phase 0).
  gemm_bias_bt<1, 0><<<dim3(64, 16), tb, 0, stream>>>(
      attn, w1, o_b, nullptr, out, nullptr, 8192, 4096, 4096, 0);
}

// Round 3
// 777.561 us; speedup vs baseline: 1.0354x; 1.0354x over previous
//
#include <hip/hip_runtime.h>

typedef unsigned short u16;
typedef short s8v __attribute__((ext_vector_type(8)));   // 8 x bf16 bits (4 VGPRs)
typedef float f32x4 __attribute__((ext_vector_type(4)));

#define MFMA16(a, b, c) __builtin_amdgcn_mfma_f32_16x16x32_bf16((a), (b), (c), 0, 0, 0)
#define GLDS16(gp, lp)                                                         \
  __builtin_amdgcn_global_load_lds(                                            \
      (const __attribute__((address_space(1))) void*)(gp),                     \
      (__attribute__((address_space(3))) void*)(lp), 16, 0, 0)

__device__ __forceinline__ float bf2f(u16 u) {
  unsigned int i = ((unsigned int)u) << 16;
  float f;
  __builtin_memcpy(&f, &i, 4);
  return f;
}
__device__ __forceinline__ u16 f2bf(float f) {
  unsigned int u;
  __builtin_memcpy(&u, &f, 4);
  unsigned int r = (u + 0x7FFFu + ((u >> 16) & 1u)) >> 16;  // RNE
  return (u16)r;
}

// ---------------- f32 -> bf16 convert (activations) -------------------------
__global__ __launch_bounds__(256) void cvt_f32_bf16(const float* __restrict__ s,
                                                    u16* __restrict__ d, long n) {
  long i = ((long)blockIdx.x * 256 + threadIdx.x) * 4;
  if (i + 3 < n) {
    float4 v = *(const float4*)(s + i);
    ushort4 o;
    o.x = f2bf(v.x); o.y = f2bf(v.y); o.z = f2bf(v.z); o.w = f2bf(v.w);
    *(ushort4*)(d + i) = o;
  }
}

// ------- batched 2048x2048 transpose + convert (f32 K-major -> bf16 N-major)
struct TransposeBatch {
  const float* src[6];
  u16* dst[6];
};

__global__ __launch_bounds__(256) void transpose2048_batch(TransposeBatch p) {
  const float* __restrict__ W = p.src[blockIdx.z];
  u16* __restrict__ Wt = p.dst[blockIdx.z];
  __shared__ u16 t[64][65];
  int c0 = blockIdx.x * 64, r0 = blockIdx.y * 64;
  int x = threadIdx.x & 63, y = threadIdx.x >> 6;
  for (int yy = y; yy < 64; yy += 4)
    t[yy][x] = f2bf(W[(long)(r0 + yy) * 2048 + c0 + x]);
  __syncthreads();
  for (int yy = y; yy < 64; yy += 4)
    Wt[(long)(c0 + yy) * 2048 + r0 + x] = t[x][yy];
}

// ---------------- GEMM: Y[M x N] = A[M x 2048] * Bt^T + bias ----------------
// DUAL=1: n in [2048,4096) goes to Yv2/bias2 (two fused output tensors).
template <int OUTF, int DUAL>
__global__ __launch_bounds__(256, 2) void gemm_bias_bt(
    const u16* __restrict__ A, const u16* __restrict__ Bt,
    const float* __restrict__ bias, const float* __restrict__ bias2,
    void* __restrict__ Yv, void* __restrict__ Yv2, int M, int rpb, int bstride,
    int roff) {
  __shared__ u16 smA[128 * 32];
  __shared__ u16 smB[128 * 32];
  const int tid = threadIdx.x;
  const int wave = tid >> 6, lane = tid & 63;
  const int lo = lane & 15, qd = lane >> 4;
  const int m0 = blockIdx.x * 128, n0 = blockIdx.y * 128;
  const int wm = (wave & 1) * 64, wn = (wave >> 1) * 64;

  const u16* aG[2];
  const u16* bG[2];
  u16* aL[2];
  u16* bL[2];
#pragma unroll
  for (int r = 0; r < 2; ++r) {
    int c = (wave * 2 + r) * 64 + lane;  // 16B chunk id, c = row*4 + seg
    int row = c >> 2, seg = c & 3;
    int gr = m0 + row;
    if (gr > M - 1) gr = M - 1;
    long grow = (long)(gr / rpb) * bstride + roff + (gr % rpb);
    aG[r] = A + grow * 2048 + seg * 8;
    bG[r] = Bt + (long)(n0 + row) * 2048 + seg * 8;
    aL[r] = smA + (wave * 2 + r) * 512;  // wave-uniform LDS base
    bL[r] = smB + (wave * 2 + r) * 512;
  }

  f32x4 acc[4][4] = {};
  for (int k0 = 0; k0 < 2048; k0 += 32) {
    GLDS16(aG[0] + k0, aL[0]);
    GLDS16(aG[1] + k0, aL[1]);
    GLDS16(bG[0] + k0, bL[0]);
    GLDS16(bG[1] + k0, bL[1]);
    __syncthreads();
    s8v af[4], bf[4];
#pragma unroll
    for (int i = 0; i < 4; i++)
      af[i] = *(const s8v*)(smA + (wm + i * 16 + lo) * 32 + qd * 8);
#pragma unroll
    for (int i = 0; i < 4; i++)
      bf[i] = *(const s8v*)(smB + (wn + i * 16 + lo) * 32 + qd * 8);
#pragma unroll
    for (int i = 0; i < 4; i++)
#pragma unroll
      for (int j = 0; j < 4; j++) acc[i][j] = MFMA16(af[i], bf[j], acc[i][j]);
    __syncthreads();
  }
#pragma unroll
  for (int j = 0; j < 4; j++) {
    int nf = n0 + wn + j * 16 + lo;
    const float* bp = bias;
    void* yp = Yv;
    int n = nf;
    if (DUAL && nf >= 2048) {
      bp = bias2;
      yp = Yv2;
      n = nf - 2048;
    }
    float bv = bp[n];
#pragma unroll
    for (int i = 0; i < 4; i++) {
      int mb = m0 + wm + i * 16 + qd * 4;
#pragma unroll
      for (int r = 0; r < 4; r++) {
        int m = mb + r;
        if (m < M) {
          float val = acc[i][j][r] + bv;
          if (OUTF)
            ((float*)yp)[(long)m * 2048 + n] = val;
          else
            ((u16*)yp)[(long)m * 2048 + n] = f2bf(val);
        }
      }
    }
  }
}

// ---------------- RMS norm over rows of 2048 (bf16 in place, f32 scale) -----
__global__ __launch_bounds__(256) void rmsnorm_rows(u16* __restrict__ X,
                                                    const float* __restrict__ sc) {
  long row = blockIdx.x;
  u16* xr = X + row * 2048;
  int tid = threadIdx.x;
  s8v v = *(const s8v*)(xr + tid * 8);
  float f[8], ss = 0.f;
#pragma unroll
  for (int j = 0; j < 8; j++) {
    f[j] = bf2f((u16)v[j]);
    ss += f[j] * f[j];
  }
  for (int o = 1; o < 64; o <<= 1) ss += __shfl_xor(ss, o);
  __shared__ float wsum[4];
  if ((tid & 63) == 0) wsum[tid >> 6] = ss;
  __syncthreads();
  float tot = wsum[0] + wsum[1] + wsum[2] + wsum[3];
  float rs = rsqrtf(tot * (1.f / 2048.f) + 1e-6f);
  float4 s0 = *(const float4*)(sc + tid * 8);
  float4 s1 = *(const float4*)(sc + tid * 8 + 4);
  float scv[8] = {s0.x, s0.y, s0.z, s0.w, s1.x, s1.y, s1.z, s1.w};
  s8v o8;
#pragma unroll
  for (int j = 0; j < 8; j++) o8[j] = (short)f2bf(f[j] * rs * scv[j]);
  *(s8v*)(xr + tid * 8) = o8;
}

// ---------------- V repack: V[b][l][h][d] -> VT[b][h][d][l] (zero-pad l) ----
__global__ __launch_bounds__(256) void repack_vt(const u16* __restrict__ V,
                                                 u16* __restrict__ VT, int L,
                                                 int Lpad) {
  int bh = blockIdx.z;  // b*16 + h
  int b = bh >> 4, h = bh & 15;
  int l0 = blockIdx.x * 64, d0 = blockIdx.y * 64;
  __shared__ u16 t[64][65];
  int x = threadIdx.x & 63, y = threadIdx.x >> 6;
  for (int yy = y; yy < 64; yy += 4) {
    int l = l0 + yy;
    u16 val = 0;
    if (l < L) val = V[((long)(b * L + l)) * 2048 + h * 128 + d0 + x];
    t[yy][x] = val;
  }
  __syncthreads();
  for (int yy = y; yy < 64; yy += 4) {
    int d = d0 + yy;
    int l = l0 + x;
    if (l < Lpad) VT[((long)bh * 128 + d) * Lpad + l] = t[x][yy];
  }
}

// ---------------- cross-attention, block-cooperative LDS-staged K/V ---------
// Round 1 was latency-bound (MfmaUtil 6.5%, VALUBusy 9.8%, HBM 9%, occ 21%):
// each wave privately gathered K and V from global (4x redundant per block),
// serial chain gload->MFMA->exp->LDS P->MFMA. Now: K tile [32 keys][128 d]
// and V tile [128 d][32 l] staged once per block into double-buffered LDS via
// global_load_lds (linear dest, PRE-SWIZZLED per-lane global source; reads
// apply the same involution -> <=2-way bank aliasing, free per m136).
// 2-phase schedule: issue stage(kt+1) -> compute kt from LDS -> syncthreads.
// K swizzle: 16B-chunk index ^ (row&7).  V swizzle: chunk ^ ((d>>1)&3).
// LDS: 2*8KB (K) + 2*8KB (V) + 20KB (P) = 52KB -> 3 blocks/CU, matches the
// (256,3) register target; bk addressing regs freed -> no spill expected.
template <int ADD, int L, int LPAD, int NT>
__global__ __launch_bounds__(256, 3) void cross_attn(
    const u16* __restrict__ Q, const u16* __restrict__ K,
    const u16* __restrict__ VT, u16* __restrict__ O) {
  const int tid = threadIdx.x, wave = tid >> 6, lane = tid & 63;
  const int lo = lane & 15, qd = lane >> 4;
  const int h = blockIdx.y, b = blockIdx.z;
  const int q0 = blockIdx.x * 128 + wave * 32;
  __shared__ u16 lk[2][32 * 128];   // [buf][key-row r][d chunk swizzled]
  __shared__ u16 lv[2][128 * 32];   // [buf][d-row][l chunk swizzled]
  __shared__ u16 pls[4][2][1280];   // [wave][parity][32 q x stride 40]

  const u16* Kb = K + ((long)b * L) * 2048 + h * 128;
  const u16* VTb = VT + ((long)(b * 16 + h)) * 128 * LPAD;

  // ---- stage helpers: 2 wave-loads each (1 KB per global_load_lds) ----
  auto stageK = [&](int pb, int kt) {
#pragma unroll
    for (int j = 0; j < 2; ++j) {
      int ci = (wave * 2 + j) * 64 + lane;  // 16B chunk id in 32x128 tile
      int r = ci >> 4, c = ci & 15;
      int key = kt * 32 + r;
      if (key > L - 1) key = L - 1;
      const u16* src = Kb + (long)key * 2048 + (c ^ (r & 7)) * 8;
      GLDS16(src, &lk[pb][(wave * 2 + j) * 512]);
    }
  };
  auto stageV = [&](int pb, int kt) {
#pragma unroll
    for (int j = 0; j < 2; ++j) {
      int ci = (wave * 2 + j) * 64 + lane;  // 16B chunk id in 128x32 tile
      int d = ci >> 2, c = ci & 3;
      const u16* src = VTb + (long)d * LPAD + kt * 32 + (c ^ ((d >> 1) & 3)) * 8;
      GLDS16(src, &lv[pb][(wave * 2 + j) * 512]);
    }
  };

  s8v aq[2][4];
#pragma unroll
  for (int qf = 0; qf < 2; ++qf) {
    const u16* qp =
        Q + ((long)(b * 4096 + q0 + qf * 16 + lo)) * 2048 + h * 128 + qd * 8;
#pragma unroll
    for (int ds = 0; ds < 4; ++ds) aq[qf][ds] = *(const s8v*)(qp + ds * 32);
  }

  const float SC = 0.08838834764831845f;  // 1/sqrt(128)
  f32x4 oacc[2][8] = {};
  float lsum[2][4] = {};

  stageK(0, 0);
  stageV(0, 0);
  __syncthreads();  // drains vmcnt(0): tile 0 resident

  const int vsw = (lo >> 1) & 3;  // V read swizzle (d&7)>>1, df*16 part is 0 mod 4

#pragma unroll 2
  for (int kt = 0; kt < NT; ++kt) {
    const int pb = kt & 1;
    if (kt + 1 < NT) {  // issue next tile's staging; lands by next barrier
      stageK(pb ^ 1, kt + 1);
      stageV(pb ^ 1, kt + 1);
    }
    // ---- K fragments from LDS (swizzled) ----
    s8v bk[2][4];
#pragma unroll
    for (int nf = 0; nf < 2; ++nf) {
      int r = nf * 16 + lo;
#pragma unroll
      for (int ds = 0; ds < 4; ++ds) {
        int cp = (ds * 4 + qd) ^ (r & 7);
        bk[nf][ds] = *(const s8v*)(&lk[pb][r * 128 + cp * 8]);
      }
    }
    // ---- QK^T ----
    f32x4 sacc[2][2] = {};
    __builtin_amdgcn_s_setprio(1);
#pragma unroll
    for (int qf = 0; qf < 2; ++qf)
#pragma unroll
      for (int nf = 0; nf < 2; ++nf)
#pragma unroll
        for (int ds = 0; ds < 4; ++ds)
          sacc[qf][nf] = MFMA16(aq[qf][ds], bk[nf][ds], sacc[qf][nf]);
    __builtin_amdgcn_s_setprio(0);
    // ---- exp (fixed offset), accumulate denominator, P -> LDS ----
    u16* pw = pls[wave][pb];
#pragma unroll
    for (int qf = 0; qf < 2; ++qf)
#pragma unroll
      for (int nf = 0; nf < 2; ++nf) {
        int key = kt * 32 + nf * 16 + lo;
        bool msk = key >= L;
#pragma unroll
        for (int r = 0; r < 4; ++r) {
          float s = fminf(fmaf(sacc[qf][nf][r], SC, -12.f), 50.f);
          float p = msk ? 0.f : __expf(s);
          lsum[qf][r] += p;
          pw[(qf * 16 + qd * 4 + r) * 40 + nf * 16 + lo] = f2bf(p);
        }
      }
    s8v pa[2];
#pragma unroll
    for (int qf = 0; qf < 2; ++qf)
      pa[qf] = *(const s8v*)(pw + (qf * 16 + lo) * 40 + qd * 8);
    // ---- P * V (V fragments from LDS, swizzled) ----
    __builtin_amdgcn_s_setprio(1);
#pragma unroll
    for (int df = 0; df < 8; ++df) {
      int d = df * 16 + lo;
      s8v bv = *(const s8v*)(&lv[pb][d * 32 + (qd ^ vsw) * 8]);
      oacc[0][df] = MFMA16(pa[0], bv, oacc[0][df]);
      oacc[1][df] = MFMA16(pa[1], bv, oacc[1][df]);
    }
    __builtin_amdgcn_s_setprio(0);
    if (kt + 1 < NT) __syncthreads();  // staged tile resident; readers done
  }
  // ---- denominator reduce (over the 16 key-lanes) + output ----
#pragma unroll
  for (int qf = 0; qf < 2; ++qf)
#pragma unroll
    for (int r = 0; r < 4; ++r) {
      float l = lsum[qf][r];
      for (int o = 1; o < 16; o <<= 1) l += __shfl_xor(l, o);
      lsum[qf][r] = 1.f / l;
    }
  u16* op = O + ((long)(b * 4096 + q0)) * 2048 + h * 128;
#pragma unroll
  for (int qf = 0; qf < 2; ++qf)
#pragma unroll
    for (int df = 0; df < 8; ++df) {
      int d = df * 16 + lo;
#pragma unroll
      for (int r = 0; r < 4; ++r) {
        long idx = (long)(qf * 16 + qd * 4 + r) * 2048 + d;
        float val = oacc[qf][df][r] * lsum[qf][r];
        if (ADD) val += bf2f(op[idx]);
        op[idx] = f2bf(val);
      }
    }
}

extern "C" void kernel_launch(void* const* d_in, const int* in_sizes, int n_in,
                              void* d_out, int out_size, void* d_ws,
                              size_t ws_size, hipStream_t stream) {
  const float* x = (const float*)d_in[0];
  const float* ctx = (const float*)d_in[1];
  const float* q_w = (const float*)d_in[2];
  const float* q_b = (const float*)d_in[3];
  const float* k_w = (const float*)d_in[4];
  const float* k_b = (const float*)d_in[5];
  const float* v_w = (const float*)d_in[6];
  const float* v_b = (const float*)d_in[7];
  const float* ki_w = (const float*)d_in[8];
  const float* ki_b = (const float*)d_in[9];
  const float* vi_w = (const float*)d_in[10];
  const float* vi_b = (const float*)d_in[11];
  const float* o_w = (const float*)d_in[12];
  const float* o_b = (const float*)d_in[13];
  const float* nq_s = (const float*)d_in[14];
  const float* nkt_s = (const float*)d_in[15];
  const float* nki_s = (const float*)d_in[16];
  float* out = (float*)d_out;
  u16* ws = (u16*)d_ws;

  // workspace layout (u16 elements); total ~103 MB
  u16* w0 = ws;                        //  4,194,304  (q_w^T)
  u16* w1 = ws + 4194304L;             //  4,194,304  (o_w^T)
  u16* q = ws + 8388608L;              // 16,777,216
  u16* attn = ws + 25165824L;          // 16,777,216
  u16* xb = attn;                      // alias (x bf16; dead before attn written)
  u16* vtxt = attn;                    // alias, 2,097,152 (dead before xb written)
  u16* vimg = attn + 2097152L;         // alias, 1,052,672
  u16* ktxt = ws + 41943040L;          //  2,097,152
  u16* kimg = ws + 44040192L;          //  1,052,672
  u16* vttxt = ws + 45092864L;         //  2,097,152 (32 x 128 x 512)
  u16* vtimg = ws + 47190016L;         //  1,179,648 (32 x 128 x 288)
  u16* ctxb = ws + 48369664L;          //  3,149,824

  dim3 tb(256);

  // Phase 0: context to bf16 + ALL weight transposes in one launch.
  cvt_f32_bf16<<<3076, tb, 0, stream>>>(ctx, ctxb, 3149824L);
  TransposeBatch tp;
  tp.src[0] = q_w;  tp.dst[0] = w0;
  tp.src[1] = o_w;  tp.dst[1] = w1;
  tp.src[2] = k_w;  tp.dst[2] = q;              // dual pair base (txt)
  tp.src[3] = v_w;  tp.dst[3] = q + 4194304L;
  tp.src[4] = ki_w; tp.dst[4] = q + 8388608L;   // dual pair base (img)
  tp.src[5] = vi_w; tp.dst[5] = q + 12582912L;
  transpose2048_batch<<<dim3(32, 32, 6), tb, 0, stream>>>(tp);

  // Phase 1: K|V projections (weights live in q region; q not written yet).
  gemm_bias_bt<0, 1><<<dim3(8, 32), tb, 0, stream>>>(
      ctxb, q, k_b, v_b, ktxt, vtxt, 1024, 512, 769, 257);
  gemm_bias_bt<0, 1><<<dim3(5, 32), tb, 0, stream>>>(
      ctxb, q + 8388608L, ki_b, vi_b, kimg, vimg, 514, 257, 769, 0);

  rmsnorm_rows<<<1024, tb, 0, stream>>>(ktxt, nkt_s);
  rmsnorm_rows<<<514, tb, 0, stream>>>(kimg, nki_s);
  repack_vt<<<dim3(8, 2, 32), tb, 0, stream>>>(vtxt, vttxt, 512, 512);
  repack_vt<<<dim3(5, 2, 32), tb, 0, stream>>>(vimg, vtimg, 257, 288);

  // Phase 2: x to bf16 (overwrites the now-repacked vtxt/vimg aliases),
  // then Q projection (output overwrites the now-dead ctx weight stages).
  cvt_f32_bf16<<<16384, tb, 0, stream>>>(x, xb, 16777216L);
  gemm_bias_bt<0, 0><<<dim3(64, 16), tb, 0, stream>>>(
      xb, w0, q_b, nullptr, q, nullptr, 8192, 4096, 4096, 0);
  rmsnorm_rows<<<8192, tb, 0, stream>>>(q, nq_s);

  // Phase 3: attention. txt writes attn (xb dead); img adds its result.
  cross_attn<0, 512, 512, 16><<<dim3(32, 16, 2), tb, 0, stream>>>(q, ktxt, vttxt, attn);
  cross_attn<1, 257, 288, 9><<<dim3(32, 16, 2), tb, 0, stream>>>(q, kimg, vtimg, attn);

  // Phase 4: output projection (o_w^T has been parked in w1 since phase 0).
  gemm_bias_bt<1, 0><<<dim3(64, 16), tb, 0, stream>>>(
      attn, w1, o_b, nullptr, out, nullptr, 8192, 4096, 4096, 0);
}

// Round 4
// 663.946 us; speedup vs baseline: 1.2126x; 1.1711x over previous
//
#include <hip/hip_runtime.h>

typedef unsigned short u16;
typedef short s8v __attribute__((ext_vector_type(8)));   // 8 x bf16 bits (4 VGPRs)
typedef float f32x4 __attribute__((ext_vector_type(4)));

#define MFMA16(a, b, c) __builtin_amdgcn_mfma_f32_16x16x32_bf16((a), (b), (c), 0, 0, 0)
#define GLDS16(gp, lp)                                                         \
  __builtin_amdgcn_global_load_lds(                                            \
      (const __attribute__((address_space(1))) void*)(gp),                     \
      (__attribute__((address_space(3))) void*)(lp), 16, 0, 0)

__device__ __forceinline__ float bf2f(u16 u) {
  unsigned int i = ((unsigned int)u) << 16;
  float f;
  __builtin_memcpy(&f, &i, 4);
  return f;
}
__device__ __forceinline__ u16 f2bf(float f) {
  unsigned int u;
  __builtin_memcpy(&u, &f, 4);
  unsigned int r = (u + 0x7FFFu + ((u >> 16) & 1u)) >> 16;  // RNE
  return (u16)r;
}

// ---------------- f32 -> bf16 convert (activations) -------------------------
__global__ __launch_bounds__(256) void cvt_f32_bf16(const float* __restrict__ s,
                                                    u16* __restrict__ d, long n) {
  long i = ((long)blockIdx.x * 256 + threadIdx.x) * 4;
  if (i + 3 < n) {
    float4 v = *(const float4*)(s + i);
    ushort4 o;
    o.x = f2bf(v.x); o.y = f2bf(v.y); o.z = f2bf(v.z); o.w = f2bf(v.w);
    *(ushort4*)(d + i) = o;
  }
}

// ------- batched 2048x2048 transpose + convert (f32 K-major -> bf16 N-major)
struct TransposeBatch {
  const float* src[6];
  u16* dst[6];
};

__global__ __launch_bounds__(256) void transpose2048_batch(TransposeBatch p) {
  const float* __restrict__ W = p.src[blockIdx.z];
  u16* __restrict__ Wt = p.dst[blockIdx.z];
  __shared__ u16 t[64][65];
  int c0 = blockIdx.x * 64, r0 = blockIdx.y * 64;
  int x = threadIdx.x & 63, y = threadIdx.x >> 6;
  for (int yy = y; yy < 64; yy += 4)
    t[yy][x] = f2bf(W[(long)(r0 + yy) * 2048 + c0 + x]);
  __syncthreads();
  for (int yy = y; yy < 64; yy += 4)
    Wt[(long)(c0 + yy) * 2048 + r0 + x] = t[x][yy];
}

// ---------------- GEMM: Y[M x N] = A[M x 2048] * Bt^T + bias ----------------
// DUAL=1: n in [2048,4096) goes to Yv2/bias2 (two fused output tensors).
template <int OUTF, int DUAL>
__global__ __launch_bounds__(256, 2) void gemm_bias_bt(
    const u16* __restrict__ A, const u16* __restrict__ Bt,
    const float* __restrict__ bias, const float* __restrict__ bias2,
    void* __restrict__ Yv, void* __restrict__ Yv2, int M, int rpb, int bstride,
    int roff) {
  __shared__ u16 smA[128 * 32];
  __shared__ u16 smB[128 * 32];
  const int tid = threadIdx.x;
  const int wave = tid >> 6, lane = tid & 63;
  const int lo = lane & 15, qd = lane >> 4;
  const int m0 = blockIdx.x * 128, n0 = blockIdx.y * 128;
  const int wm = (wave & 1) * 64, wn = (wave >> 1) * 64;

  const u16* aG[2];
  const u16* bG[2];
  u16* aL[2];
  u16* bL[2];
#pragma unroll
  for (int r = 0; r < 2; ++r) {
    int c = (wave * 2 + r) * 64 + lane;  // 16B chunk id, c = row*4 + seg
    int row = c >> 2, seg = c & 3;
    int gr = m0 + row;
    if (gr > M - 1) gr = M - 1;
    long grow = (long)(gr / rpb) * bstride + roff + (gr % rpb);
    aG[r] = A + grow * 2048 + seg * 8;
    bG[r] = Bt + (long)(n0 + row) * 2048 + seg * 8;
    aL[r] = smA + (wave * 2 + r) * 512;  // wave-uniform LDS base
    bL[r] = smB + (wave * 2 + r) * 512;
  }

  f32x4 acc[4][4] = {};
  for (int k0 = 0; k0 < 2048; k0 += 32) {
    GLDS16(aG[0] + k0, aL[0]);
    GLDS16(aG[1] + k0, aL[1]);
    GLDS16(bG[0] + k0, bL[0]);
    GLDS16(bG[1] + k0, bL[1]);
    __syncthreads();
    s8v af[4], bf[4];
#pragma unroll
    for (int i = 0; i < 4; i++)
      af[i] = *(const s8v*)(smA + (wm + i * 16 + lo) * 32 + qd * 8);
#pragma unroll
    for (int i = 0; i < 4; i++)
      bf[i] = *(const s8v*)(smB + (wn + i * 16 + lo) * 32 + qd * 8);
#pragma unroll
    for (int i = 0; i < 4; i++)
#pragma unroll
      for (int j = 0; j < 4; j++) acc[i][j] = MFMA16(af[i], bf[j], acc[i][j]);
    __syncthreads();
  }
#pragma unroll
  for (int j = 0; j < 4; j++) {
    int nf = n0 + wn + j * 16 + lo;
    const float* bp = bias;
    void* yp = Yv;
    int n = nf;
    if (DUAL && nf >= 2048) {
      bp = bias2;
      yp = Yv2;
      n = nf - 2048;
    }
    float bv = bp[n];
#pragma unroll
    for (int i = 0; i < 4; i++) {
      int mb = m0 + wm + i * 16 + qd * 4;
#pragma unroll
      for (int r = 0; r < 4; r++) {
        int m = mb + r;
        if (m < M) {
          float val = acc[i][j][r] + bv;
          if (OUTF)
            ((float*)yp)[(long)m * 2048 + n] = val;
          else
            ((u16*)yp)[(long)m * 2048 + n] = f2bf(val);
        }
      }
    }
  }
}

// ---------------- RMS norm over rows of 2048 (bf16 in place, f32 scale) -----
__global__ __launch_bounds__(256) void rmsnorm_rows(u16* __restrict__ X,
                                                    const float* __restrict__ sc) {
  long row = blockIdx.x;
  u16* xr = X + row * 2048;
  int tid = threadIdx.x;
  s8v v = *(const s8v*)(xr + tid * 8);
  float f[8], ss = 0.f;
#pragma unroll
  for (int j = 0; j < 8; j++) {
    f[j] = bf2f((u16)v[j]);
    ss += f[j] * f[j];
  }
  for (int o = 1; o < 64; o <<= 1) ss += __shfl_xor(ss, o);
  __shared__ float wsum[4];
  if ((tid & 63) == 0) wsum[tid >> 6] = ss;
  __syncthreads();
  float tot = wsum[0] + wsum[1] + wsum[2] + wsum[3];
  float rs = rsqrtf(tot * (1.f / 2048.f) + 1e-6f);
  float4 s0 = *(const float4*)(sc + tid * 8);
  float4 s1 = *(const float4*)(sc + tid * 8 + 4);
  float scv[8] = {s0.x, s0.y, s0.z, s0.w, s1.x, s1.y, s1.z, s1.w};
  s8v o8;
#pragma unroll
  for (int j = 0; j < 8; j++) o8[j] = (short)f2bf(f[j] * rs * scv[j]);
  *(s8v*)(xr + tid * 8) = o8;
}

// ---------------- V repack: V[b][l][h][d] -> VT[b][h][d][l] (zero-pad l) ----
__global__ __launch_bounds__(256) void repack_vt(const u16* __restrict__ V,
                                                 u16* __restrict__ VT, int L,
                                                 int Lpad) {
  int bh = blockIdx.z;  // b*16 + h
  int b = bh >> 4, h = bh & 15;
  int l0 = blockIdx.x * 64, d0 = blockIdx.y * 64;
  __shared__ u16 t[64][65];
  int x = threadIdx.x & 63, y = threadIdx.x >> 6;
  for (int yy = y; yy < 64; yy += 4) {
    int l = l0 + yy;
    u16 val = 0;
    if (l < L) val = V[((long)(b * L + l)) * 2048 + h * 128 + d0 + x];
    t[yy][x] = val;
  }
  __syncthreads();
  for (int yy = y; yy < 64; yy += 4) {
    int d = d0 + yy;
    int l = l0 + x;
    if (l < Lpad) VT[((long)bh * 128 + d) * Lpad + l] = t[x][yy];
  }
}

// ---------------- fused txt+img cross-attention -----------------------------
// Round 3 counters: txt and img dispatches BOTH ~127us (fixed cost dominates);
// FETCH ~100MB each (Q 32 + K,V at 8x XCD-L2 redundancy), WRITE ~72MB (32B
// scattered stores = 2x amplification on 64B granules); img re-reads Q + attn.
// v3: ONE kernel, sequential txt (16 tiles) then img (9 tiles) passes over the
// same in-register Q; separate accumulators/denominators (reference norms the
// two softmaxes independently); combine in f32 in the epilogue; coalesced
// 256B-row writes via LDS-staged transpose; XCD-family block remap so all 32
// q-tile blocks sharing (b,h) K/V land on one XCD L2 (K/V fetched ~once).
// Cost: 128 AGPR accumulators -> launch_bounds(256,2) (2 waves/SIMD).
template <int LT, int LPT, int NTT, int LI, int LPI, int NTI>
__global__ __launch_bounds__(256, 2) void cross_attn_fused(
    const u16* __restrict__ Q, const u16* __restrict__ Kt,
    const u16* __restrict__ VTt, const u16* __restrict__ Ki,
    const u16* __restrict__ VTi, u16* __restrict__ O) {
  const int tid = threadIdx.x, wave = tid >> 6, lane = tid & 63;
  const int lo = lane & 15, qd = lane >> 4;
  // XCD-family decode: id%8 -> XCD (round-robin dispatch); family f=(h,b) gets
  // all 32 of its q-tile blocks on one XCD; 4 families/XCD (~1.6MB K/V in L2).
  const int id = blockIdx.x;                 // 1024 blocks
  const int xp = id & 7, xr = id >> 3;       // xp: XCD slot, xr in [0,128)
  const int t = xr & 31;                     // q-tile
  const int f = xp * 4 + (xr >> 5);          // family in [0,32)
  const int h = f & 15, b = f >> 4;
  const int q0 = t * 128 + wave * 32;

  __shared__ u16 smem[26624];                // 52 KB
  u16* lk = smem;                            // 2 bufs x 4096 u16 (K tile)
  u16* lv = smem + 8192;                     // 2 bufs x 4096 u16 (V tile)
  u16* pls = smem + 16384;                   // [wave][parity][1280] P slice

  const u16* Kbt = Kt + ((long)b * LT) * 2048 + h * 128;
  const u16* VTbt = VTt + ((long)(b * 16 + h)) * 128 * LPT;
  const u16* Kbi = Ki + ((long)b * LI) * 2048 + h * 128;
  const u16* VTbi = VTi + ((long)(b * 16 + h)) * 128 * LPI;

  // stage global tile gt (0..NTT-1: txt, NTT..NTT+NTI-1: img) into buf pb.
  // Linear LDS dest + involution-swizzled global source (rule #21).
  auto stage = [&](int pb, int gt) {
    const u16* Kb;
    const u16* VTb;
    int kt, L, LPAD;
    if (gt < NTT) {
      Kb = Kbt; VTb = VTbt; kt = gt; L = LT; LPAD = LPT;
    } else {
      Kb = Kbi; VTb = VTbi; kt = gt - NTT; L = LI; LPAD = LPI;
    }
#pragma unroll
    for (int j = 0; j < 2; ++j) {
      int ci = (wave * 2 + j) * 64 + lane;   // 16B chunk id in 32x128 K tile
      int r = ci >> 4, c = ci & 15;
      int key = kt * 32 + r;
      if (key > L - 1) key = L - 1;
      const u16* src = Kb + (long)key * 2048 + (c ^ (r & 7)) * 8;
      GLDS16(src, &lk[pb * 4096 + (wave * 2 + j) * 512]);
    }
#pragma unroll
    for (int j = 0; j < 2; ++j) {
      int ci = (wave * 2 + j) * 64 + lane;   // 16B chunk id in 128x32 V tile
      int d = ci >> 2, c = ci & 3;
      const u16* src = VTb + (long)d * LPAD + kt * 32 + (c ^ ((d >> 1) & 3)) * 8;
      GLDS16(src, &lv[pb * 4096 + (wave * 2 + j) * 512]);
    }
  };

  s8v aq[2][4];
#pragma unroll
  for (int qf = 0; qf < 2; ++qf) {
    const u16* qp =
        Q + ((long)(b * 4096 + q0 + qf * 16 + lo)) * 2048 + h * 128 + qd * 8;
#pragma unroll
    for (int ds = 0; ds < 4; ++ds) aq[qf][ds] = *(const s8v*)(qp + ds * 32);
  }

  const float SC = 0.08838834764831845f;  // 1/sqrt(128)
  const int vsw = (lo >> 1) & 3;          // V read swizzle
  f32x4 oT[2][8] = {}, oI[2][8] = {};
  float lsT[2][4] = {}, lsI[2][4] = {};

  // one K-tile step: LDS reads -> QK^T -> exp -> P LDS roundtrip -> PV.
  // acc arrays bound by name per pass (all indices compile-time; rule #20).
  auto tile_step = [&](int pb, int ktile, int Lcur, f32x4 (&oacc)[2][8],
                       float (&lsum)[2][4]) {
    s8v bk[2][4];
#pragma unroll
    for (int nf = 0; nf < 2; ++nf) {
      int r = nf * 16 + lo;
#pragma unroll
      for (int ds = 0; ds < 4; ++ds) {
        int cp = (ds * 4 + qd) ^ (r & 7);
        bk[nf][ds] = *(const s8v*)(&lk[pb * 4096 + r * 128 + cp * 8]);
      }
    }
    f32x4 sacc[2][2] = {};
    __builtin_amdgcn_s_setprio(1);
#pragma unroll
    for (int qf = 0; qf < 2; ++qf)
#pragma unroll
      for (int nf = 0; nf < 2; ++nf)
#pragma unroll
        for (int ds = 0; ds < 4; ++ds)
          sacc[qf][nf] = MFMA16(aq[qf][ds], bk[nf][ds], sacc[qf][nf]);
    __builtin_amdgcn_s_setprio(0);
    u16* pw = pls + wave * 2560 + pb * 1280;
#pragma unroll
    for (int qf = 0; qf < 2; ++qf)
#pragma unroll
      for (int nf = 0; nf < 2; ++nf) {
        int key = ktile * 32 + nf * 16 + lo;
        bool msk = key >= Lcur;
#pragma unroll
        for (int r = 0; r < 4; ++r) {
          float s = fminf(fmaf(sacc[qf][nf][r], SC, -12.f), 50.f);
          float p = msk ? 0.f : __expf(s);
          lsum[qf][r] += p;
          pw[(qf * 16 + qd * 4 + r) * 40 + nf * 16 + lo] = f2bf(p);
        }
      }
    s8v pa[2];
#pragma unroll
    for (int qf = 0; qf < 2; ++qf)
      pa[qf] = *(const s8v*)(pw + (qf * 16 + lo) * 40 + qd * 8);
    __builtin_amdgcn_s_setprio(1);
#pragma unroll
    for (int df = 0; df < 8; ++df) {
      int d = df * 16 + lo;
      s8v bv = *(const s8v*)(&lv[pb * 4096 + d * 32 + (qd ^ vsw) * 8]);
      oacc[0][df] = MFMA16(pa[0], bv, oacc[0][df]);
      oacc[1][df] = MFMA16(pa[1], bv, oacc[1][df]);
    }
    __builtin_amdgcn_s_setprio(0);
  };

  stage(0, 0);
  __syncthreads();  // tile 0 resident

  // txt pass: iteration NTT-1 stages img tile 0 (gt=NTT) into the other buf.
#pragma unroll 2
  for (int kt = 0; kt < NTT; ++kt) {
    const int pb = kt & 1;
    stage(pb ^ 1, kt + 1);
    tile_step(pb, kt, LT, oT, lsT);
    __syncthreads();
  }
  // img pass: parity continues (NTT even -> img tile 0 in buf 0).
#pragma unroll 2
  for (int kt = 0; kt < NTI; ++kt) {
    const int pb = kt & 1;
    if (kt + 1 < NTI) stage(pb ^ 1, NTT + kt + 1);
    tile_step(pb, kt, LI, oI, lsI);
    if (kt + 1 < NTI) __syncthreads();
  }

  // ---- denominators (reduce over the 16 key-lanes), combine, write ----
#pragma unroll
  for (int qf = 0; qf < 2; ++qf)
#pragma unroll
    for (int r = 0; r < 4; ++r) {
      float a = lsT[qf][r], c = lsI[qf][r];
      for (int o = 1; o < 16; o <<= 1) {
        a += __shfl_xor(a, o);
        c += __shfl_xor(c, o);
      }
      lsT[qf][r] = 1.f / a;
      lsI[qf][r] = 1.f / c;
    }
  __syncthreads();  // all waves done with lk/lv/pls; reuse smem for epilogue
  // stage wave's 32x128 output tile (stride 136 u16: qd-groups 2-way max bank
  // alias = free), then write 256B-contiguous rows: 2 lanes x 128B per row.
  u16* ep = smem + wave * 4352;
#pragma unroll
  for (int qf = 0; qf < 2; ++qf)
#pragma unroll
    for (int df = 0; df < 8; ++df)
#pragma unroll
      for (int r = 0; r < 4; ++r) {
        float val = oT[qf][df][r] * lsT[qf][r] + oI[qf][df][r] * lsI[qf][r];
        ep[(qf * 16 + qd * 4 + r) * 136 + df * 16 + lo] = f2bf(val);
      }
  const int row = lane >> 1, half = lane & 1;
  const u16* srcp = ep + row * 136 + half * 64;
  u16* gdst = O + ((long)(b * 4096 + q0 + row)) * 2048 + h * 128 + half * 64;
#pragma unroll
  for (int c = 0; c < 8; ++c) *(s8v*)(gdst + c * 8) = *(const s8v*)(srcp + c * 8);
}

extern "C" void kernel_launch(void* const* d_in, const int* in_sizes, int n_in,
                              void* d_out, int out_size, void* d_ws,
                              size_t ws_size, hipStream_t stream) {
  const float* x = (const float*)d_in[0];
  const float* ctx = (const float*)d_in[1];
  const float* q_w = (const float*)d_in[2];
  const float* q_b = (const float*)d_in[3];
  const float* k_w = (const float*)d_in[4];
  const float* k_b = (const float*)d_in[5];
  const float* v_w = (const float*)d_in[6];
  const float* v_b = (const float*)d_in[7];
  const float* ki_w = (const float*)d_in[8];
  const float* ki_b = (const float*)d_in[9];
  const float* vi_w = (const float*)d_in[10];
  const float* vi_b = (const float*)d_in[11];
  const float* o_w = (const float*)d_in[12];
  const float* o_b = (const float*)d_in[13];
  const float* nq_s = (const float*)d_in[14];
  const float* nkt_s = (const float*)d_in[15];
  const float* nki_s = (const float*)d_in[16];
  float* out = (float*)d_out;
  u16* ws = (u16*)d_ws;

  // workspace layout (u16 elements); total ~103 MB
  u16* w0 = ws;                        //  4,194,304  (q_w^T)
  u16* w1 = ws + 4194304L;             //  4,194,304  (o_w^T)
  u16* q = ws + 8388608L;              // 16,777,216
  u16* attn = ws + 25165824L;          // 16,777,216
  u16* xb = attn;                      // alias (x bf16; dead before attn written)
  u16* vtxt = attn;                    // alias, 2,097,152 (dead before xb written)
  u16* vimg = attn + 2097152L;         // alias, 1,052,672
  u16* ktxt = ws + 41943040L;          //  2,097,152
  u16* kimg = ws + 44040192L;          //  1,052,672
  u16* vttxt = ws + 45092864L;         //  2,097,152 (32 x 128 x 512)
  u16* vtimg = ws + 47190016L;         //  1,179,648 (32 x 128 x 288)
  u16* ctxb = ws + 48369664L;          //  3,149,824

  dim3 tb(256);

  // Phase 0: context to bf16 + ALL weight transposes in one launch.
  cvt_f32_bf16<<<3076, tb, 0, stream>>>(ctx, ctxb, 3149824L);
  TransposeBatch tp;
  tp.src[0] = q_w;  tp.dst[0] = w0;
  tp.src[1] = o_w;  tp.dst[1] = w1;
  tp.src[2] = k_w;  tp.dst[2] = q;              // dual pair base (txt)
  tp.src[3] = v_w;  tp.dst[3] = q + 4194304L;
  tp.src[4] = ki_w; tp.dst[4] = q + 8388608L;   // dual pair base (img)
  tp.src[5] = vi_w; tp.dst[5] = q + 12582912L;
  transpose2048_batch<<<dim3(32, 32, 6), tb, 0, stream>>>(tp);

  // Phase 1: K|V projections (weights live in q region; q not written yet).
  gemm_bias_bt<0, 1><<<dim3(8, 32), tb, 0, stream>>>(
      ctxb, q, k_b, v_b, ktxt, vtxt, 1024, 512, 769, 257);
  gemm_bias_bt<0, 1><<<dim3(5, 32), tb, 0, stream>>>(
      ctxb, q + 8388608L, ki_b, vi_b, kimg, vimg, 514, 257, 769, 0);

  rmsnorm_rows<<<1024, tb, 0, stream>>>(ktxt, nkt_s);
  rmsnorm_rows<<<514, tb, 0, stream>>>(kimg, nki_s);
  repack_vt<<<dim3(8, 2, 32), tb, 0, stream>>>(vtxt, vttxt, 512, 512);
  repack_vt<<<dim3(5, 2, 32), tb, 0, stream>>>(vimg, vtimg, 257, 288);

  // Phase 2: x to bf16 (overwrites the now-repacked vtxt/vimg aliases),
  // then Q projection (output overwrites the now-dead ctx weight stages).
  cvt_f32_bf16<<<16384, tb, 0, stream>>>(x, xb, 16777216L);
  gemm_bias_bt<0, 0><<<dim3(64, 16), tb, 0, stream>>>(
      xb, w0, q_b, nullptr, q, nullptr, 8192, 4096, 4096, 0);
  rmsnorm_rows<<<8192, tb, 0, stream>>>(q, nq_s);

  // Phase 3: fused attention (txt + img in one dispatch, single attn write).
  cross_attn_fused<512, 512, 16, 257, 288, 9><<<1024, tb, 0, stream>>>(
      q, ktxt, vttxt, kimg, vtimg, attn);

  // Phase 4: output projection (o_w^T has been parked in w1 since phase 0).
  gemm_bias_bt<1, 0><<<dim3(64, 16), tb, 0, stream>>>(
      attn, w1, o_b, nullptr, out, nullptr, 8192, 4096, 4096, 0);
}

// Round 5
// 626.447 us; speedup vs baseline: 1.2852x; 1.0599x over previous
//
#include <hip/hip_runtime.h>

typedef unsigned short u16;
typedef short s8v __attribute__((ext_vector_type(8)));   // 8 x bf16 bits (4 VGPRs)
typedef float f32x4 __attribute__((ext_vector_type(4)));

#define MFMA16(a, b, c) __builtin_amdgcn_mfma_f32_16x16x32_bf16((a), (b), (c), 0, 0, 0)
#define GLDS16(gp, lp)                                                         \
  __builtin_amdgcn_global_load_lds(                                            \
      (const __attribute__((address_space(1))) void*)(gp),                     \
      (__attribute__((address_space(3))) void*)(lp), 16, 0, 0)

__device__ __forceinline__ float bf2f(u16 u) {
  unsigned int i = ((unsigned int)u) << 16;
  float f;
  __builtin_memcpy(&f, &i, 4);
  return f;
}
__device__ __forceinline__ u16 f2bf(float f) {
  unsigned int u;
  __builtin_memcpy(&u, &f, 4);
  unsigned int r = (u + 0x7FFFu + ((u >> 16) & 1u)) >> 16;  // RNE
  return (u16)r;
}

// ---------------- f32 -> bf16 convert (activations) -------------------------
__global__ __launch_bounds__(256) void cvt_f32_bf16(const float* __restrict__ s,
                                                    u16* __restrict__ d, long n) {
  long i = ((long)blockIdx.x * 256 + threadIdx.x) * 4;
  if (i + 3 < n) {
    float4 v = *(const float4*)(s + i);
    ushort4 o;
    o.x = f2bf(v.x); o.y = f2bf(v.y); o.z = f2bf(v.z); o.w = f2bf(v.w);
    *(ushort4*)(d + i) = o;
  }
}

// ------- batched 2048x2048 transpose + convert (f32 K-major -> bf16 N-major)
struct TransposeBatch {
  const float* src[6];
  u16* dst[6];
};

__global__ __launch_bounds__(256) void transpose2048_batch(TransposeBatch p) {
  const float* __restrict__ W = p.src[blockIdx.z];
  u16* __restrict__ Wt = p.dst[blockIdx.z];
  __shared__ u16 t[64][65];
  int c0 = blockIdx.x * 64, r0 = blockIdx.y * 64;
  int x = threadIdx.x & 63, y = threadIdx.x >> 6;
  for (int yy = y; yy < 64; yy += 4)
    t[yy][x] = f2bf(W[(long)(r0 + yy) * 2048 + c0 + x]);
  __syncthreads();
  for (int yy = y; yy < 64; yy += 4)
    Wt[(long)(c0 + yy) * 2048 + r0 + x] = t[x][yy];
}

// ---------------- GEMM: Y[M x N] = A[M x 2048] * Bt^T + bias ----------------
// DUAL=1: n in [2048,4096) goes to Yv2/bias2 (two fused output tensors).
template <int OUTF, int DUAL>
__global__ __launch_bounds__(256, 2) void gemm_bias_bt(
    const u16* __restrict__ A, const u16* __restrict__ Bt,
    const float* __restrict__ bias, const float* __restrict__ bias2,
    void* __restrict__ Yv, void* __restrict__ Yv2, int M, int rpb, int bstride,
    int roff) {
  __shared__ u16 smA[128 * 32];
  __shared__ u16 smB[128 * 32];
  const int tid = threadIdx.x;
  const int wave = tid >> 6, lane = tid & 63;
  const int lo = lane & 15, qd = lane >> 4;
  const int m0 = blockIdx.x * 128, n0 = blockIdx.y * 128;
  const int wm = (wave & 1) * 64, wn = (wave >> 1) * 64;

  const u16* aG[2];
  const u16* bG[2];
  u16* aL[2];
  u16* bL[2];
#pragma unroll
  for (int r = 0; r < 2; ++r) {
    int c = (wave * 2 + r) * 64 + lane;  // 16B chunk id, c = row*4 + seg
    int row = c >> 2, seg = c & 3;
    int gr = m0 + row;
    if (gr > M - 1) gr = M - 1;
    long grow = (long)(gr / rpb) * bstride + roff + (gr % rpb);
    aG[r] = A + grow * 2048 + seg * 8;
    bG[r] = Bt + (long)(n0 + row) * 2048 + seg * 8;
    aL[r] = smA + (wave * 2 + r) * 512;  // wave-uniform LDS base
    bL[r] = smB + (wave * 2 + r) * 512;
  }

  f32x4 acc[4][4] = {};
  for (int k0 = 0; k0 < 2048; k0 += 32) {
    GLDS16(aG[0] + k0, aL[0]);
    GLDS16(aG[1] + k0, aL[1]);
    GLDS16(bG[0] + k0, bL[0]);
    GLDS16(bG[1] + k0, bL[1]);
    __syncthreads();
    s8v af[4], bf[4];
#pragma unroll
    for (int i = 0; i < 4; i++)
      af[i] = *(const s8v*)(smA + (wm + i * 16 + lo) * 32 + qd * 8);
#pragma unroll
    for (int i = 0; i < 4; i++)
      bf[i] = *(const s8v*)(smB + (wn + i * 16 + lo) * 32 + qd * 8);
#pragma unroll
    for (int i = 0; i < 4; i++)
#pragma unroll
      for (int j = 0; j < 4; j++) acc[i][j] = MFMA16(af[i], bf[j], acc[i][j]);
    __syncthreads();
  }
#pragma unroll
  for (int j = 0; j < 4; j++) {
    int nf = n0 + wn + j * 16 + lo;
    const float* bp = bias;
    void* yp = Yv;
    int n = nf;
    if (DUAL && nf >= 2048) {
      bp = bias2;
      yp = Yv2;
      n = nf - 2048;
    }
    float bv = bp[n];
#pragma unroll
    for (int i = 0; i < 4; i++) {
      int mb = m0 + wm + i * 16 + qd * 4;
#pragma unroll
      for (int r = 0; r < 4; r++) {
        int m = mb + r;
        if (m < M) {
          float val = acc[i][j][r] + bv;
          if (OUTF)
            ((float*)yp)[(long)m * 2048 + n] = val;
          else
            ((u16*)yp)[(long)m * 2048 + n] = f2bf(val);
        }
      }
    }
  }
}

// ---------------- RMS norm over rows of 2048 (bf16 in place, f32 scale) -----
__global__ __launch_bounds__(256) void rmsnorm_rows(u16* __restrict__ X,
                                                    const float* __restrict__ sc) {
  long row = blockIdx.x;
  u16* xr = X + row * 2048;
  int tid = threadIdx.x;
  s8v v = *(const s8v*)(xr + tid * 8);
  float f[8], ss = 0.f;
#pragma unroll
  for (int j = 0; j < 8; j++) {
    f[j] = bf2f((u16)v[j]);
    ss += f[j] * f[j];
  }
  for (int o = 1; o < 64; o <<= 1) ss += __shfl_xor(ss, o);
  __shared__ float wsum[4];
  if ((tid & 63) == 0) wsum[tid >> 6] = ss;
  __syncthreads();
  float tot = wsum[0] + wsum[1] + wsum[2] + wsum[3];
  float rs = rsqrtf(tot * (1.f / 2048.f) + 1e-6f);
  float4 s0 = *(const float4*)(sc + tid * 8);
  float4 s1 = *(const float4*)(sc + tid * 8 + 4);
  float scv[8] = {s0.x, s0.y, s0.z, s0.w, s1.x, s1.y, s1.z, s1.w};
  s8v o8;
#pragma unroll
  for (int j = 0; j < 8; j++) o8[j] = (short)f2bf(f[j] * rs * scv[j]);
  *(s8v*)(xr + tid * 8) = o8;
}

// ---------------- V repack: V[b][l][h][d] -> VT[b][h][d][l] (zero-pad l) ----
__global__ __launch_bounds__(256) void repack_vt(const u16* __restrict__ V,
                                                 u16* __restrict__ VT, int L,
                                                 int Lpad) {
  int bh = blockIdx.z;  // b*16 + h
  int b = bh >> 4, h = bh & 15;
  int l0 = blockIdx.x * 64, d0 = blockIdx.y * 64;
  __shared__ u16 t[64][65];
  int x = threadIdx.x & 63, y = threadIdx.x >> 6;
  for (int yy = y; yy < 64; yy += 4) {
    int l = l0 + yy;
    u16 val = 0;
    if (l < L) val = V[((long)(b * L + l)) * 2048 + h * 128 + d0 + x];
    t[yy][x] = val;
  }
  __syncthreads();
  for (int yy = y; yy < 64; yy += 4) {
    int d = d0 + yy;
    int l = l0 + x;
    if (l < Lpad) VT[((long)bh * 128 + d) * Lpad + l] = t[x][yy];
  }
}

// ---------------- fused txt+img cross-attention, spill-free -----------------
// Round 4 counters: WRITE 116.7MB (ideal 32) + FETCH 64.9 (ideal 44) = ~100MB
// scratch spill: oT+oI = 128 f32 accumulators live together hit the (256,2)
// reg cap. v4: after the txt pass, reduce lsT, NORMALIZE oT and park it in
// LDS as bf16 (bf16 intermediate validated by round-3's ADD kernel: identical
// absmax). oT's 64 regs die before oI is born -> peak pressure ~150 regs, no
// spill. P slice single-buffered (same-wave write->read, in-order DS pipe +
// compiler lgkmcnt; parity was redundant). LDS: K/V dbuf 32KB + P 10KB + oT
// stage 34KB (stride-136 rows) = 76KB -> still 2 blocks/CU.
template <int LT, int LPT, int NTT, int LI, int LPI, int NTI>
__global__ __launch_bounds__(256, 2) void cross_attn_fused(
    const u16* __restrict__ Q, const u16* __restrict__ Kt,
    const u16* __restrict__ VTt, const u16* __restrict__ Ki,
    const u16* __restrict__ VTi, u16* __restrict__ O) {
  const int tid = threadIdx.x, wave = tid >> 6, lane = tid & 63;
  const int lo = lane & 15, qd = lane >> 4;
  // XCD-family decode: id%8 -> XCD (round-robin dispatch); family f=(h,b) gets
  // all 32 of its q-tile blocks on one XCD; 4 families/XCD (~1.6MB K/V in L2).
  const int id = blockIdx.x;                 // 1024 blocks
  const int xp = id & 7, xr = id >> 3;       // xp: XCD slot, xr in [0,128)
  const int t = xr & 31;                     // q-tile
  const int f = xp * 4 + (xr >> 5);          // family in [0,32)
  const int h = f & 15, b = f >> 4;
  const int q0 = t * 128 + wave * 32;

  __shared__ u16 smem[38912];                // 76 KB
  u16* lk = smem;                            // 2 bufs x 4096 u16 (K tile)
  u16* lv = smem + 8192;                     // 2 bufs x 4096 u16 (V tile)
  u16* pls = smem + 16384;                   // [wave][1280] P slice (single)
  u16* oTs = smem + 21504;                   // [wave][4352] txt result stage

  const u16* Kbt = Kt + ((long)b * LT) * 2048 + h * 128;
  const u16* VTbt = VTt + ((long)(b * 16 + h)) * 128 * LPT;
  const u16* Kbi = Ki + ((long)b * LI) * 2048 + h * 128;
  const u16* VTbi = VTi + ((long)(b * 16 + h)) * 128 * LPI;

  // stage global tile gt (0..NTT-1: txt, NTT..NTT+NTI-1: img) into buf pb.
  // Linear LDS dest + involution-swizzled global source (rule #21).
  auto stage = [&](int pb, int gt) {
    const u16* Kb;
    const u16* VTb;
    int kt, L, LPAD;
    if (gt < NTT) {
      Kb = Kbt; VTb = VTbt; kt = gt; L = LT; LPAD = LPT;
    } else {
      Kb = Kbi; VTb = VTbi; kt = gt - NTT; L = LI; LPAD = LPI;
    }
#pragma unroll
    for (int j = 0; j < 2; ++j) {
      int ci = (wave * 2 + j) * 64 + lane;   // 16B chunk id in 32x128 K tile
      int r = ci >> 4, c = ci & 15;
      int key = kt * 32 + r;
      if (key > L - 1) key = L - 1;
      const u16* src = Kb + (long)key * 2048 + (c ^ (r & 7)) * 8;
      GLDS16(src, &lk[pb * 4096 + (wave * 2 + j) * 512]);
    }
#pragma unroll
    for (int j = 0; j < 2; ++j) {
      int ci = (wave * 2 + j) * 64 + lane;   // 16B chunk id in 128x32 V tile
      int d = ci >> 2, c = ci & 3;
      const u16* src = VTb + (long)d * LPAD + kt * 32 + (c ^ ((d >> 1) & 3)) * 8;
      GLDS16(src, &lv[pb * 4096 + (wave * 2 + j) * 512]);
    }
  };

  s8v aq[2][4];
#pragma unroll
  for (int qf = 0; qf < 2; ++qf) {
    const u16* qp =
        Q + ((long)(b * 4096 + q0 + qf * 16 + lo)) * 2048 + h * 128 + qd * 8;
#pragma unroll
    for (int ds = 0; ds < 4; ++ds) aq[qf][ds] = *(const s8v*)(qp + ds * 32);
  }

  const float SC = 0.08838834764831845f;  // 1/sqrt(128)
  const int vsw = (lo >> 1) & 3;          // V read swizzle

  // one K-tile step: LDS reads -> QK^T -> exp -> P LDS roundtrip -> PV.
  auto tile_step = [&](int pb, int ktile, int Lcur, f32x4 (&oacc)[2][8],
                       float (&lsum)[2][4]) {
    s8v bk[2][4];
#pragma unroll
    for (int nf = 0; nf < 2; ++nf) {
      int r = nf * 16 + lo;
#pragma unroll
      for (int ds = 0; ds < 4; ++ds) {
        int cp = (ds * 4 + qd) ^ (r & 7);
        bk[nf][ds] = *(const s8v*)(&lk[pb * 4096 + r * 128 + cp * 8]);
      }
    }
    f32x4 sacc[2][2] = {};
    __builtin_amdgcn_s_setprio(1);
#pragma unroll
    for (int qf = 0; qf < 2; ++qf)
#pragma unroll
      for (int nf = 0; nf < 2; ++nf)
#pragma unroll
        for (int ds = 0; ds < 4; ++ds)
          sacc[qf][nf] = MFMA16(aq[qf][ds], bk[nf][ds], sacc[qf][nf]);
    __builtin_amdgcn_s_setprio(0);
    u16* pw = pls + wave * 1280;
#pragma unroll
    for (int qf = 0; qf < 2; ++qf)
#pragma unroll
      for (int nf = 0; nf < 2; ++nf) {
        int key = ktile * 32 + nf * 16 + lo;
        bool msk = key >= Lcur;
#pragma unroll
        for (int r = 0; r < 4; ++r) {
          float s = fminf(fmaf(sacc[qf][nf][r], SC, -12.f), 50.f);
          float p = msk ? 0.f : __expf(s);
          lsum[qf][r] += p;
          pw[(qf * 16 + qd * 4 + r) * 40 + nf * 16 + lo] = f2bf(p);
        }
      }
    s8v pa[2];
#pragma unroll
    for (int qf = 0; qf < 2; ++qf)
      pa[qf] = *(const s8v*)(pw + (qf * 16 + lo) * 40 + qd * 8);
    __builtin_amdgcn_s_setprio(1);
#pragma unroll
    for (int df = 0; df < 8; ++df) {
      int d = df * 16 + lo;
      s8v bv = *(const s8v*)(&lv[pb * 4096 + d * 32 + (qd ^ vsw) * 8]);
      oacc[0][df] = MFMA16(pa[0], bv, oacc[0][df]);
      oacc[1][df] = MFMA16(pa[1], bv, oacc[1][df]);
    }
    __builtin_amdgcn_s_setprio(0);
  };

  stage(0, 0);
  __syncthreads();  // tile 0 resident

  u16* ep = oTs + wave * 4352;

  // ---- txt pass (iteration NTT-1 stages img tile 0 into the other buf) ----
  {
    f32x4 oT[2][8] = {};
    float lsT[2][4] = {};
#pragma unroll 2
    for (int kt = 0; kt < NTT; ++kt) {
      const int pb = kt & 1;
      stage(pb ^ 1, kt + 1);
      tile_step(pb, kt, LT, oT, lsT);
      __syncthreads();
    }
    // normalize and park in LDS as bf16; oT registers die here.
#pragma unroll
    for (int qf = 0; qf < 2; ++qf)
#pragma unroll
      for (int r = 0; r < 4; ++r) {
        float a = lsT[qf][r];
        for (int o = 1; o < 16; o <<= 1) a += __shfl_xor(a, o);
        lsT[qf][r] = 1.f / a;
      }
#pragma unroll
    for (int qf = 0; qf < 2; ++qf)
#pragma unroll
      for (int df = 0; df < 8; ++df)
#pragma unroll
        for (int r = 0; r < 4; ++r)
          ep[(qf * 16 + qd * 4 + r) * 136 + df * 16 + lo] =
              f2bf(oT[qf][df][r] * lsT[qf][r]);
  }

  // ---- img pass (parity continues: NTT even -> img tile 0 in buf 0) ----
  f32x4 oI[2][8] = {};
  float lsI[2][4] = {};
#pragma unroll 2
  for (int kt = 0; kt < NTI; ++kt) {
    const int pb = kt & 1;
    if (kt + 1 < NTI) stage(pb ^ 1, NTT + kt + 1);
    tile_step(pb, kt, LI, oI, lsI);
    if (kt + 1 < NTI) __syncthreads();
  }

  // ---- img denominator, combine with parked txt result, coalesced write ----
#pragma unroll
  for (int qf = 0; qf < 2; ++qf)
#pragma unroll
    for (int r = 0; r < 4; ++r) {
      float c = lsI[qf][r];
      for (int o = 1; o < 16; o <<= 1) c += __shfl_xor(c, o);
      lsI[qf][r] = 1.f / c;
    }
  // wave-private read-modify-write of the parked tile (no barrier needed)
#pragma unroll
  for (int qf = 0; qf < 2; ++qf)
#pragma unroll
    for (int df = 0; df < 8; ++df)
#pragma unroll
      for (int r = 0; r < 4; ++r) {
        int idx = (qf * 16 + qd * 4 + r) * 136 + df * 16 + lo;
        float val = bf2f(ep[idx]) + oI[qf][df][r] * lsI[qf][r];
        ep[idx] = f2bf(val);
      }
  // coalesced write: 2 lanes x 128B per row, 256B-contiguous segments
  const int row = lane >> 1, half = lane & 1;
  const u16* srcp = ep + row * 136 + half * 64;
  u16* gdst = O + ((long)(b * 4096 + q0 + row)) * 2048 + h * 128 + half * 64;
#pragma unroll
  for (int c = 0; c < 8; ++c) *(s8v*)(gdst + c * 8) = *(const s8v*)(srcp + c * 8);
}

extern "C" void kernel_launch(void* const* d_in, const int* in_sizes, int n_in,
                              void* d_out, int out_size, void* d_ws,
                              size_t ws_size, hipStream_t stream) {
  const float* x = (const float*)d_in[0];
  const float* ctx = (const float*)d_in[1];
  const float* q_w = (const float*)d_in[2];
  const float* q_b = (const float*)d_in[3];
  const float* k_w = (const float*)d_in[4];
  const float* k_b = (const float*)d_in[5];
  const float* v_w = (const float*)d_in[6];
  const float* v_b = (const float*)d_in[7];
  const float* ki_w = (const float*)d_in[8];
  const float* ki_b = (const float*)d_in[9];
  const float* vi_w = (const float*)d_in[10];
  const float* vi_b = (const float*)d_in[11];
  const float* o_w = (const float*)d_in[12];
  const float* o_b = (const float*)d_in[13];
  const float* nq_s = (const float*)d_in[14];
  const float* nkt_s = (const float*)d_in[15];
  const float* nki_s = (const float*)d_in[16];
  float* out = (float*)d_out;
  u16* ws = (u16*)d_ws;

  // workspace layout (u16 elements); total ~103 MB
  u16* w0 = ws;                        //  4,194,304  (q_w^T)
  u16* w1 = ws + 4194304L;             //  4,194,304  (o_w^T)
  u16* q = ws + 8388608L;              // 16,777,216
  u16* attn = ws + 25165824L;          // 16,777,216
  u16* xb = attn;                      // alias (x bf16; dead before attn written)
  u16* vtxt = attn;                    // alias, 2,097,152 (dead before xb written)
  u16* vimg = attn + 2097152L;         // alias, 1,052,672
  u16* ktxt = ws + 41943040L;          //  2,097,152
  u16* kimg = ws + 44040192L;          //  1,052,672
  u16* vttxt = ws + 45092864L;         //  2,097,152 (32 x 128 x 512)
  u16* vtimg = ws + 47190016L;         //  1,179,648 (32 x 128 x 288)
  u16* ctxb = ws + 48369664L;          //  3,149,824

  dim3 tb(256);

  // Phase 0: context to bf16 + ALL weight transposes in one launch.
  cvt_f32_bf16<<<3076, tb, 0, stream>>>(ctx, ctxb, 3149824L);
  TransposeBatch tp;
  tp.src[0] = q_w;  tp.dst[0] = w0;
  tp.src[1] = o_w;  tp.dst[1] = w1;
  tp.src[2] = k_w;  tp.dst[2] = q;              // dual pair base (txt)
  tp.src[3] = v_w;  tp.dst[3] = q + 4194304L;
  tp.src[4] = ki_w; tp.dst[4] = q + 8388608L;   // dual pair base (img)
  tp.src[5] = vi_w; tp.dst[5] = q + 12582912L;
  transpose2048_batch<<<dim3(32, 32, 6), tb, 0, stream>>>(tp);

  // Phase 1: K|V projections (weights live in q region; q not written yet).
  gemm_bias_bt<0, 1><<<dim3(8, 32), tb, 0, stream>>>(
      ctxb, q, k_b, v_b, ktxt, vtxt, 1024, 512, 769, 257);
  gemm_bias_bt<0, 1><<<dim3(5, 32), tb, 0, stream>>>(
      ctxb, q + 8388608L, ki_b, vi_b, kimg, vimg, 514, 257, 769, 0);

  rmsnorm_rows<<<1024, tb, 0, stream>>>(ktxt, nkt_s);
  rmsnorm_rows<<<514, tb, 0, stream>>>(kimg, nki_s);
  repack_vt<<<dim3(8, 2, 32), tb, 0, stream>>>(vtxt, vttxt, 512, 512);
  repack_vt<<<dim3(5, 2, 32), tb, 0, stream>>>(vimg, vtimg, 257, 288);

  // Phase 2: x to bf16 (overwrites the now-repacked vtxt/vimg aliases),
  // then Q projection (output overwrites the now-dead ctx weight stages).
  cvt_f32_bf16<<<16384, tb, 0, stream>>>(x, xb, 16777216L);
  gemm_bias_bt<0, 0><<<dim3(64, 16), tb, 0, stream>>>(
      xb, w0, q_b, nullptr, q, nullptr, 8192, 4096, 4096, 0);
  rmsnorm_rows<<<8192, tb, 0, stream>>>(q, nq_s);

  // Phase 3: fused attention (txt + img in one dispatch, single attn write).
  cross_attn_fused<512, 512, 16, 257, 288, 9><<<1024, tb, 0, stream>>>(
      q, ktxt, vttxt, kimg, vtimg, attn);

  // Phase 4: output projection (o_w^T has been parked in w1 since phase 0).
  gemm_bias_bt<1, 0><<<dim3(64, 16), tb, 0, stream>>>(
      attn, w1, o_b, nullptr, out, nullptr, 8192, 4096, 4096, 0);
}

// Round 6
// 575.497 us; speedup vs baseline: 1.3990x; 1.0885x over previous
//
#include <hip/hip_runtime.h>

typedef unsigned short u16;
typedef short s8v __attribute__((ext_vector_type(8)));   // 8 x bf16 bits (4 VGPRs)
typedef float f32x4 __attribute__((ext_vector_type(4)));

#define MFMA16(a, b, c) __builtin_amdgcn_mfma_f32_16x16x32_bf16((a), (b), (c), 0, 0, 0)
#define GLDS16(gp, lp)                                                         \
  __builtin_amdgcn_global_load_lds(                                            \
      (const __attribute__((address_space(1))) void*)(gp),                     \
      (__attribute__((address_space(3))) void*)(lp), 16, 0, 0)

__device__ __forceinline__ float bf2f(u16 u) {
  unsigned int i = ((unsigned int)u) << 16;
  float f;
  __builtin_memcpy(&f, &i, 4);
  return f;
}
__device__ __forceinline__ u16 f2bf(float f) {
  unsigned int u;
  __builtin_memcpy(&u, &f, 4);
  unsigned int r = (u + 0x7FFFu + ((u >> 16) & 1u)) >> 16;  // RNE
  return (u16)r;
}

// ---------------- f32 -> bf16 convert (activations) -------------------------
__global__ __launch_bounds__(256) void cvt_f32_bf16(const float* __restrict__ s,
                                                    u16* __restrict__ d, long n) {
  long i = ((long)blockIdx.x * 256 + threadIdx.x) * 4;
  if (i + 3 < n) {
    float4 v = *(const float4*)(s + i);
    ushort4 o;
    o.x = f2bf(v.x); o.y = f2bf(v.y); o.z = f2bf(v.z); o.w = f2bf(v.w);
    *(ushort4*)(d + i) = o;
  }
}

// ------- batched 2048x2048 transpose + convert (f32 K-major -> bf16 N-major)
struct TransposeBatch {
  const float* src[6];
  u16* dst[6];
};

__global__ __launch_bounds__(256) void transpose2048_batch(TransposeBatch p) {
  const float* __restrict__ W = p.src[blockIdx.z];
  u16* __restrict__ Wt = p.dst[blockIdx.z];
  __shared__ u16 t[64][65];
  int c0 = blockIdx.x * 64, r0 = blockIdx.y * 64;
  int x = threadIdx.x & 63, y = threadIdx.x >> 6;
  for (int yy = y; yy < 64; yy += 4)
    t[yy][x] = f2bf(W[(long)(r0 + yy) * 2048 + c0 + x]);
  __syncthreads();
  for (int yy = y; yy < 64; yy += 4)
    Wt[(long)(c0 + yy) * 2048 + r0 + x] = t[x][yy];
}

// ---------------- GEMM (legacy 128x128): kept for the small KV projections --
// DUAL=1: n in [2048,4096) goes to Yv2/bias2 (two fused output tensors).
template <int OUTF, int DUAL>
__global__ __launch_bounds__(256, 2) void gemm_bias_bt(
    const u16* __restrict__ A, const u16* __restrict__ Bt,
    const float* __restrict__ bias, const float* __restrict__ bias2,
    void* __restrict__ Yv, void* __restrict__ Yv2, int M, int rpb, int bstride,
    int roff) {
  __shared__ u16 smA[128 * 32];
  __shared__ u16 smB[128 * 32];
  const int tid = threadIdx.x;
  const int wave = tid >> 6, lane = tid & 63;
  const int lo = lane & 15, qd = lane >> 4;
  const int m0 = blockIdx.x * 128, n0 = blockIdx.y * 128;
  const int wm = (wave & 1) * 64, wn = (wave >> 1) * 64;

  const u16* aG[2];
  const u16* bG[2];
  u16* aL[2];
  u16* bL[2];
#pragma unroll
  for (int r = 0; r < 2; ++r) {
    int c = (wave * 2 + r) * 64 + lane;  // 16B chunk id, c = row*4 + seg
    int row = c >> 2, seg = c & 3;
    int gr = m0 + row;
    if (gr > M - 1) gr = M - 1;
    long grow = (long)(gr / rpb) * bstride + roff + (gr % rpb);
    aG[r] = A + grow * 2048 + seg * 8;
    bG[r] = Bt + (long)(n0 + row) * 2048 + seg * 8;
    aL[r] = smA + (wave * 2 + r) * 512;  // wave-uniform LDS base
    bL[r] = smB + (wave * 2 + r) * 512;
  }

  f32x4 acc[4][4] = {};
  for (int k0 = 0; k0 < 2048; k0 += 32) {
    GLDS16(aG[0] + k0, aL[0]);
    GLDS16(aG[1] + k0, aL[1]);
    GLDS16(bG[0] + k0, bL[0]);
    GLDS16(bG[1] + k0, bL[1]);
    __syncthreads();
    s8v af[4], bf[4];
#pragma unroll
    for (int i = 0; i < 4; i++)
      af[i] = *(const s8v*)(smA + (wm + i * 16 + lo) * 32 + qd * 8);
#pragma unroll
    for (int i = 0; i < 4; i++)
      bf[i] = *(const s8v*)(smB + (wn + i * 16 + lo) * 32 + qd * 8);
#pragma unroll
    for (int i = 0; i < 4; i++)
#pragma unroll
      for (int j = 0; j < 4; j++) acc[i][j] = MFMA16(af[i], bf[j], acc[i][j]);
    __syncthreads();
  }
#pragma unroll
  for (int j = 0; j < 4; j++) {
    int nf = n0 + wn + j * 16 + lo;
    const float* bp = bias;
    void* yp = Yv;
    int n = nf;
    if (DUAL && nf >= 2048) {
      bp = bias2;
      yp = Yv2;
      n = nf - 2048;
    }
    float bv = bp[n];
#pragma unroll
    for (int i = 0; i < 4; i++) {
      int mb = m0 + wm + i * 16 + qd * 4;
#pragma unroll
      for (int r = 0; r < 4; r++) {
        int m = mb + r;
        if (m < M) {
          float val = acc[i][j][r] + bv;
          if (OUTF)
            ((float*)yp)[(long)m * 2048 + n] = val;
          else
            ((u16*)yp)[(long)m * 2048 + n] = f2bf(val);
        }
      }
    }
  }
}

// ---------------- GEMM 256x256 / BK=64, phase-split K-loop ------------------
// For the two M=8192, N=2048, K=2048 projections (A strictly linear).
// Ladder step 128^2-2ph -> 256^2 phase-split (m198/m201/m218): 8 waves (2Mx4N),
// per-wave 128x64 out (acc[8][4] = 128 VGPR), LDS 128KB = 2dbuf x [256][64]
// A+B. Stage via global_load_lds: LINEAR LDS dest + involution source swizzle
// chunk^(row&7) (rule #21; same proven pattern as cross_attn) -> all frag
// ds_read_b128 land <=2-way bank alias (free, m136). Per K-tile: 2 phases
// {12 ds_read -> issue 4 GLDS of next tile -> setprio(1) 32 MFMA setprio(0)
// -> raw s_barrier}; per-wave vmcnt(0) ONCE per K-tile (raw barriers avoid
// the compiler's __syncthreads full drain; T4). Prologue: 2-tile prefetch,
// counted vmcnt(8). Numerics identical to legacy GEMM (same frag math, f32
// accum, RNE) -> absmax must not move.
template <int OUTF>
__global__ __launch_bounds__(512, 2) void gemm256(
    const u16* __restrict__ A, const u16* __restrict__ Bt,
    const float* __restrict__ bias, void* __restrict__ Yv) {
  __shared__ u16 smA[2][16384];  // [dbuf][256 rows x 64 k] (64KB)
  __shared__ u16 smB[2][16384];  // (64KB)
  const int tid = threadIdx.x;
  const int wave = tid >> 6, lane = tid & 63;
  const int lo = lane & 15, qd = lane >> 4;
  const int m0 = blockIdx.x * 256, n0 = blockIdx.y * 256;
  const int wm = (wave >> 2) * 128, wn = (wave & 3) * 64;
  const int wbase = (tid & ~63);  // wave*64, lane-uniform

  // stage half of tile t (4 of 8 GLDS) into buf b. 2048 chunks of 16B per
  // 256x64 tile; chunk ci = row*8 + c; source col pre-swizzled c^(row&7).
  auto stage_h = [&](int b, int t, int half) {
#pragma unroll
    for (int j = half * 2; j < half * 2 + 2; ++j) {
      int ci = j * 512 + tid;
      int r = ci >> 3, c = ci & 7;
      GLDS16(A + (long)(m0 + r) * 2048 + t * 64 + ((c ^ (r & 7)) << 3),
             &smA[b][(j * 512 + wbase) * 8]);
    }
#pragma unroll
    for (int j = half * 2; j < half * 2 + 2; ++j) {
      int ci = j * 512 + tid;
      int r = ci >> 3, c = ci & 7;
      GLDS16(Bt + (long)(n0 + r) * 2048 + t * 64 + ((c ^ (r & 7)) << 3),
             &smB[b][(j * 512 + wbase) * 8]);
    }
  };
  // fragment readers: row stride 64 elems (8 chunks); swizzled chunk index.
  auto rdA = [&](int b, int ks, int mf) {
    int r = wm + mf * 16 + lo;
    int sc = (ks * 4 + qd) ^ (r & 7);
    return *(const s8v*)(&smA[b][r * 64 + sc * 8]);
  };
  auto rdB = [&](int b, int ks, int nf) {
    int r = wn + nf * 16 + lo;
    int sc = (ks * 4 + qd) ^ (r & 7);
    return *(const s8v*)(&smB[b][r * 64 + sc * 8]);
  };

  f32x4 acc[8][4] = {};
  stage_h(0, 0, 0); stage_h(0, 0, 1);   // tile 0 -> buf 0 (8 loads)
  stage_h(1, 1, 0); stage_h(1, 1, 1);   // tile 1 -> buf 1 (8 loads)
  asm volatile("s_waitcnt vmcnt(8)" ::: "memory");  // tile 0 landed
  __builtin_amdgcn_s_barrier();

  for (int t = 0; t < 32; ++t) {
    const int b = t & 1;
    s8v af[8], bf[4];
    // ---- phase 0 (k-step 0) ----
#pragma unroll
    for (int mf = 0; mf < 8; ++mf) af[mf] = rdA(b, 0, mf);
#pragma unroll
    for (int nf = 0; nf < 4; ++nf) bf[nf] = rdB(b, 0, nf);
    if (t < 31) stage_h(b ^ 1, t + 1, 0);
    __builtin_amdgcn_s_setprio(1);
#pragma unroll
    for (int mf = 0; mf < 8; ++mf)
#pragma unroll
      for (int nf = 0; nf < 4; ++nf)
        acc[mf][nf] = MFMA16(af[mf], bf[nf], acc[mf][nf]);
    __builtin_amdgcn_s_setprio(0);
    __builtin_amdgcn_s_barrier();  // pacing: waves alternate LDS<->MFMA
    // ---- phase 1 (k-step 1) ----
#pragma unroll
    for (int mf = 0; mf < 8; ++mf) af[mf] = rdA(b, 1, mf);
#pragma unroll
    for (int nf = 0; nf < 4; ++nf) bf[nf] = rdB(b, 1, nf);
    if (t < 31) stage_h(b ^ 1, t + 1, 1);
    __builtin_amdgcn_s_setprio(1);
#pragma unroll
    for (int mf = 0; mf < 8; ++mf)
#pragma unroll
      for (int nf = 0; nf < 4; ++nf)
        acc[mf][nf] = MFMA16(af[mf], bf[nf], acc[mf][nf]);
    __builtin_amdgcn_s_setprio(0);
    asm volatile("s_waitcnt vmcnt(0)" ::: "memory");  // next tile resident
    __builtin_amdgcn_s_barrier();
  }

  // ---- epilogue: bias + store (f32 rows coalesce to 64B granules) ----
#pragma unroll
  for (int nf = 0; nf < 4; ++nf) {
    int n = n0 + wn + nf * 16 + lo;
    float bv = bias[n];
#pragma unroll
    for (int mf = 0; mf < 8; ++mf) {
      int mb = m0 + wm + mf * 16 + qd * 4;
#pragma unroll
      for (int r = 0; r < 4; ++r) {
        float val = acc[mf][nf][r] + bv;
        if (OUTF)
          ((float*)Yv)[(long)(mb + r) * 2048 + n] = val;
        else
          ((u16*)Yv)[(long)(mb + r) * 2048 + n] = f2bf(val);
      }
    }
  }
}

// ---------------- RMS norm over rows of 2048 (bf16 in place, f32 scale) -----
__global__ __launch_bounds__(256) void rmsnorm_rows(u16* __restrict__ X,
                                                    const float* __restrict__ sc) {
  long row = blockIdx.x;
  u16* xr = X + row * 2048;
  int tid = threadIdx.x;
  s8v v = *(const s8v*)(xr + tid * 8);
  float f[8], ss = 0.f;
#pragma unroll
  for (int j = 0; j < 8; j++) {
    f[j] = bf2f((u16)v[j]);
    ss += f[j] * f[j];
  }
  for (int o = 1; o < 64; o <<= 1) ss += __shfl_xor(ss, o);
  __shared__ float wsum[4];
  if ((tid & 63) == 0) wsum[tid >> 6] = ss;
  __syncthreads();
  float tot = wsum[0] + wsum[1] + wsum[2] + wsum[3];
  float rs = rsqrtf(tot * (1.f / 2048.f) + 1e-6f);
  float4 s0 = *(const float4*)(sc + tid * 8);
  float4 s1 = *(const float4*)(sc + tid * 8 + 4);
  float scv[8] = {s0.x, s0.y, s0.z, s0.w, s1.x, s1.y, s1.z, s1.w};
  s8v o8;
#pragma unroll
  for (int j = 0; j < 8; j++) o8[j] = (short)f2bf(f[j] * rs * scv[j]);
  *(s8v*)(xr + tid * 8) = o8;
}

// ---------------- V repack: V[b][l][h][d] -> VT[b][h][d][l] (zero-pad l) ----
__global__ __launch_bounds__(256) void repack_vt(const u16* __restrict__ V,
                                                 u16* __restrict__ VT, int L,
                                                 int Lpad) {
  int bh = blockIdx.z;  // b*16 + h
  int b = bh >> 4, h = bh & 15;
  int l0 = blockIdx.x * 64, d0 = blockIdx.y * 64;
  __shared__ u16 t[64][65];
  int x = threadIdx.x & 63, y = threadIdx.x >> 6;
  for (int yy = y; yy < 64; yy += 4) {
    int l = l0 + yy;
    u16 val = 0;
    if (l < L) val = V[((long)(b * L + l)) * 2048 + h * 128 + d0 + x];
    t[yy][x] = val;
  }
  __syncthreads();
  for (int yy = y; yy < 64; yy += 4) {
    int d = d0 + yy;
    int l = l0 + x;
    if (l < Lpad) VT[((long)bh * 128 + d) * Lpad + l] = t[x][yy];
  }
}

// ---------------- fused txt+img cross-attention, spill-free -----------------
// (unchanged from round 5: 105us, FETCH 33.5MB, WRITE 55MB, MfmaUtil 20%)
template <int LT, int LPT, int NTT, int LI, int LPI, int NTI>
__global__ __launch_bounds__(256, 2) void cross_attn_fused(
    const u16* __restrict__ Q, const u16* __restrict__ Kt,
    const u16* __restrict__ VTt, const u16* __restrict__ Ki,
    const u16* __restrict__ VTi, u16* __restrict__ O) {
  const int tid = threadIdx.x, wave = tid >> 6, lane = tid & 63;
  const int lo = lane & 15, qd = lane >> 4;
  const int id = blockIdx.x;                 // 1024 blocks
  const int xp = id & 7, xr = id >> 3;       // xp: XCD slot, xr in [0,128)
  const int t = xr & 31;                     // q-tile
  const int f = xp * 4 + (xr >> 5);          // family in [0,32)
  const int h = f & 15, b = f >> 4;
  const int q0 = t * 128 + wave * 32;

  __shared__ u16 smem[38912];                // 76 KB
  u16* lk = smem;                            // 2 bufs x 4096 u16 (K tile)
  u16* lv = smem + 8192;                     // 2 bufs x 4096 u16 (V tile)
  u16* pls = smem + 16384;                   // [wave][1280] P slice (single)
  u16* oTs = smem + 21504;                   // [wave][4352] txt result stage

  const u16* Kbt = Kt + ((long)b * LT) * 2048 + h * 128;
  const u16* VTbt = VTt + ((long)(b * 16 + h)) * 128 * LPT;
  const u16* Kbi = Ki + ((long)b * LI) * 2048 + h * 128;
  const u16* VTbi = VTi + ((long)(b * 16 + h)) * 128 * LPI;

  auto stage = [&](int pb, int gt) {
    const u16* Kb;
    const u16* VTb;
    int kt, L, LPAD;
    if (gt < NTT) {
      Kb = Kbt; VTb = VTbt; kt = gt; L = LT; LPAD = LPT;
    } else {
      Kb = Kbi; VTb = VTbi; kt = gt - NTT; L = LI; LPAD = LPI;
    }
#pragma unroll
    for (int j = 0; j < 2; ++j) {
      int ci = (wave * 2 + j) * 64 + lane;   // 16B chunk id in 32x128 K tile
      int r = ci >> 4, c = ci & 15;
      int key = kt * 32 + r;
      if (key > L - 1) key = L - 1;
      const u16* src = Kb + (long)key * 2048 + (c ^ (r & 7)) * 8;
      GLDS16(src, &lk[pb * 4096 + (wave * 2 + j) * 512]);
    }
#pragma unroll
    for (int j = 0; j < 2; ++j) {
      int ci = (wave * 2 + j) * 64 + lane;   // 16B chunk id in 128x32 V tile
      int d = ci >> 2, c = ci & 3;
      const u16* src = VTb + (long)d * LPAD + kt * 32 + (c ^ ((d >> 1) & 3)) * 8;
      GLDS16(src, &lv[pb * 4096 + (wave * 2 + j) * 512]);
    }
  };

  s8v aq[2][4];
#pragma unroll
  for (int qf = 0; qf < 2; ++qf) {
    const u16* qp =
        Q + ((long)(b * 4096 + q0 + qf * 16 + lo)) * 2048 + h * 128 + qd * 8;
#pragma unroll
    for (int ds = 0; ds < 4; ++ds) aq[qf][ds] = *(const s8v*)(qp + ds * 32);
  }

  const float SC = 0.08838834764831845f;  // 1/sqrt(128)
  const int vsw = (lo >> 1) & 3;          // V read swizzle

  auto tile_step = [&](int pb, int ktile, int Lcur, f32x4 (&oacc)[2][8],
                       float (&lsum)[2][4]) {
    s8v bk[2][4];
#pragma unroll
    for (int nf = 0; nf < 2; ++nf) {
      int r = nf * 16 + lo;
#pragma unroll
      for (int ds = 0; ds < 4; ++ds) {
        int cp = (ds * 4 + qd) ^ (r & 7);
        bk[nf][ds] = *(const s8v*)(&lk[pb * 4096 + r * 128 + cp * 8]);
      }
    }
    f32x4 sacc[2][2] = {};
    __builtin_amdgcn_s_setprio(1);
#pragma unroll
    for (int qf = 0; qf < 2; ++qf)
#pragma unroll
      for (int nf = 0; nf < 2; ++nf)
#pragma unroll
        for (int ds = 0; ds < 4; ++ds)
          sacc[qf][nf] = MFMA16(aq[qf][ds], bk[nf][ds], sacc[qf][nf]);
    __builtin_amdgcn_s_setprio(0);
    u16* pw = pls + wave * 1280;
#pragma unroll
    for (int qf = 0; qf < 2; ++qf)
#pragma unroll
      for (int nf = 0; nf < 2; ++nf) {
        int key = ktile * 32 + nf * 16 + lo;
        bool msk = key >= Lcur;
#pragma unroll
        for (int r = 0; r < 4; ++r) {
          float s = fminf(fmaf(sacc[qf][nf][r], SC, -12.f), 50.f);
          float p = msk ? 0.f : __expf(s);
          lsum[qf][r] += p;
          pw[(qf * 16 + qd * 4 + r) * 40 + nf * 16 + lo] = f2bf(p);
        }
      }
    s8v pa[2];
#pragma unroll
    for (int qf = 0; qf < 2; ++qf)
      pa[qf] = *(const s8v*)(pw + (qf * 16 + lo) * 40 + qd * 8);
    __builtin_amdgcn_s_setprio(1);
#pragma unroll
    for (int df = 0; df < 8; ++df) {
      int d = df * 16 + lo;
      s8v bv = *(const s8v*)(&lv[pb * 4096 + d * 32 + (qd ^ vsw) * 8]);
      oacc[0][df] = MFMA16(pa[0], bv, oacc[0][df]);
      oacc[1][df] = MFMA16(pa[1], bv, oacc[1][df]);
    }
    __builtin_amdgcn_s_setprio(0);
  };

  stage(0, 0);
  __syncthreads();  // tile 0 resident

  u16* ep = oTs + wave * 4352;

  // ---- txt pass (iteration NTT-1 stages img tile 0 into the other buf) ----
  {
    f32x4 oT[2][8] = {};
    float lsT[2][4] = {};
#pragma unroll 2
    for (int kt = 0; kt < NTT; ++kt) {
      const int pb = kt & 1;
      stage(pb ^ 1, kt + 1);
      tile_step(pb, kt, LT, oT, lsT);
      __syncthreads();
    }
    // normalize and park in LDS as bf16; oT registers die here.
#pragma unroll
    for (int qf = 0; qf < 2; ++qf)
#pragma unroll
      for (int r = 0; r < 4; ++r) {
        float a = lsT[qf][r];
        for (int o = 1; o < 16; o <<= 1) a += __shfl_xor(a, o);
        lsT[qf][r] = 1.f / a;
      }
#pragma unroll
    for (int qf = 0; qf < 2; ++qf)
#pragma unroll
      for (int df = 0; df < 8; ++df)
#pragma unroll
        for (int r = 0; r < 4; ++r)
          ep[(qf * 16 + qd * 4 + r) * 136 + df * 16 + lo] =
              f2bf(oT[qf][df][r] * lsT[qf][r]);
  }

  // ---- img pass (parity continues: NTT even -> img tile 0 in buf 0) ----
  f32x4 oI[2][8] = {};
  float lsI[2][4] = {};
#pragma unroll 2
  for (int kt = 0; kt < NTI; ++kt) {
    const int pb = kt & 1;
    if (kt + 1 < NTI) stage(pb ^ 1, NTT + kt + 1);
    tile_step(pb, kt, LI, oI, lsI);
    if (kt + 1 < NTI) __syncthreads();
  }

  // ---- img denominator, combine with parked txt result, coalesced write ----
#pragma unroll
  for (int qf = 0; qf < 2; ++qf)
#pragma unroll
    for (int r = 0; r < 4; ++r) {
      float c = lsI[qf][r];
      for (int o = 1; o < 16; o <<= 1) c += __shfl_xor(c, o);
      lsI[qf][r] = 1.f / c;
    }
#pragma unroll
  for (int qf = 0; qf < 2; ++qf)
#pragma unroll
    for (int df = 0; df < 8; ++df)
#pragma unroll
      for (int r = 0; r < 4; ++r) {
        int idx = (qf * 16 + qd * 4 + r) * 136 + df * 16 + lo;
        float val = bf2f(ep[idx]) + oI[qf][df][r] * lsI[qf][r];
        ep[idx] = f2bf(val);
      }
  const int row = lane >> 1, half = lane & 1;
  const u16* srcp = ep + row * 136 + half * 64;
  u16* gdst = O + ((long)(b * 4096 + q0 + row)) * 2048 + h * 128 + half * 64;
#pragma unroll
  for (int c = 0; c < 8; ++c) *(s8v*)(gdst + c * 8) = *(const s8v*)(srcp + c * 8);
}

extern "C" void kernel_launch(void* const* d_in, const int* in_sizes, int n_in,
                              void* d_out, int out_size, void* d_ws,
                              size_t ws_size, hipStream_t stream) {
  const float* x = (const float*)d_in[0];
  const float* ctx = (const float*)d_in[1];
  const float* q_w = (const float*)d_in[2];
  const float* q_b = (const float*)d_in[3];
  const float* k_w = (const float*)d_in[4];
  const float* k_b = (const float*)d_in[5];
  const float* v_w = (const float*)d_in[6];
  const float* v_b = (const float*)d_in[7];
  const float* ki_w = (const float*)d_in[8];
  const float* ki_b = (const float*)d_in[9];
  const float* vi_w = (const float*)d_in[10];
  const float* vi_b = (const float*)d_in[11];
  const float* o_w = (const float*)d_in[12];
  const float* o_b = (const float*)d_in[13];
  const float* nq_s = (const float*)d_in[14];
  const float* nkt_s = (const float*)d_in[15];
  const float* nki_s = (const float*)d_in[16];
  float* out = (float*)d_out;
  u16* ws = (u16*)d_ws;

  // workspace layout (u16 elements); total ~103 MB
  u16* w0 = ws;                        //  4,194,304  (q_w^T)
  u16* w1 = ws + 4194304L;             //  4,194,304  (o_w^T)
  u16* q = ws + 8388608L;              // 16,777,216
  u16* attn = ws + 25165824L;          // 16,777,216
  u16* xb = attn;                      // alias (x bf16; dead before attn written)
  u16* vtxt = attn;                    // alias, 2,097,152 (dead before xb written)
  u16* vimg = attn + 2097152L;         // alias, 1,052,672
  u16* ktxt = ws + 41943040L;          //  2,097,152
  u16* kimg = ws + 44040192L;          //  1,052,672
  u16* vttxt = ws + 45092864L;         //  2,097,152 (32 x 128 x 512)
  u16* vtimg = ws + 47190016L;         //  1,179,648 (32 x 128 x 288)
  u16* ctxb = ws + 48369664L;          //  3,149,824

  dim3 tb(256);

  // Phase 0: context to bf16 + ALL weight transposes in one launch.
  cvt_f32_bf16<<<3076, tb, 0, stream>>>(ctx, ctxb, 3149824L);
  TransposeBatch tp;
  tp.src[0] = q_w;  tp.dst[0] = w0;
  tp.src[1] = o_w;  tp.dst[1] = w1;
  tp.src[2] = k_w;  tp.dst[2] = q;              // dual pair base (txt)
  tp.src[3] = v_w;  tp.dst[3] = q + 4194304L;
  tp.src[4] = ki_w; tp.dst[4] = q + 8388608L;   // dual pair base (img)
  tp.src[5] = vi_w; tp.dst[5] = q + 12582912L;
  transpose2048_batch<<<dim3(32, 32, 6), tb, 0, stream>>>(tp);

  // Phase 1: K|V projections (weights live in q region; q not written yet).
  gemm_bias_bt<0, 1><<<dim3(8, 32), tb, 0, stream>>>(
      ctxb, q, k_b, v_b, ktxt, vtxt, 1024, 512, 769, 257);
  gemm_bias_bt<0, 1><<<dim3(5, 32), tb, 0, stream>>>(
      ctxb, q + 8388608L, ki_b, vi_b, kimg, vimg, 514, 257, 769, 0);

  rmsnorm_rows<<<1024, tb, 0, stream>>>(ktxt, nkt_s);
  rmsnorm_rows<<<514, tb, 0, stream>>>(kimg, nki_s);
  repack_vt<<<dim3(8, 2, 32), tb, 0, stream>>>(vtxt, vttxt, 512, 512);
  repack_vt<<<dim3(5, 2, 32), tb, 0, stream>>>(vimg, vtimg, 257, 288);

  // Phase 2: x to bf16 (overwrites the now-repacked vtxt/vimg aliases),
  // then Q projection on the 256^2 phase-split kernel.
  cvt_f32_bf16<<<16384, tb, 0, stream>>>(x, xb, 16777216L);
  gemm256<0><<<dim3(32, 8), dim3(512), 0, stream>>>(xb, w0, q_b, q);
  rmsnorm_rows<<<8192, tb, 0, stream>>>(q, nq_s);

  // Phase 3: fused attention (txt + img in one dispatch, single attn write).
  cross_attn_fused<512, 512, 16, 257, 288, 9><<<1024, tb, 0, stream>>>(
      q, ktxt, vttxt, kimg, vtimg, attn);

  // Phase 4: output projection on the 256^2 phase-split kernel.
  gemm256<1><<<dim3(32, 8), dim3(512), 0, stream>>>(attn, w1, o_b, out);
}

// Round 8
// 566.223 us; speedup vs baseline: 1.4219x; 1.0164x over previous
//
#include <hip/hip_runtime.h>

typedef unsigned short u16;
typedef short s8v __attribute__((ext_vector_type(8)));   // 8 x bf16 bits (4 VGPRs)
typedef float f32x4 __attribute__((ext_vector_type(4)));

#define MFMA16(a, b, c) __builtin_amdgcn_mfma_f32_16x16x32_bf16((a), (b), (c), 0, 0, 0)
#define GLDS16(gp, lp)                                                         \
  __builtin_amdgcn_global_load_lds(                                            \
      (const __attribute__((address_space(1))) void*)(gp),                     \
      (__attribute__((address_space(3))) void*)(lp), 16, 0, 0)

__device__ __forceinline__ float bf2f(u16 u) {
  unsigned int i = ((unsigned int)u) << 16;
  float f;
  __builtin_memcpy(&f, &i, 4);
  return f;
}
__device__ __forceinline__ u16 f2bf(float f) {
  unsigned int u;
  __builtin_memcpy(&u, &f, 4);
  unsigned int r = (u + 0x7FFFu + ((u >> 16) & 1u)) >> 16;  // RNE
  return (u16)r;
}

template <bool B>
struct MaskTag {
  static constexpr bool do_mask = B;
};

// ---------------- f32 -> bf16 convert (activations) -------------------------
__global__ __launch_bounds__(256) void cvt_f32_bf16(const float* __restrict__ s,
                                                    u16* __restrict__ d, long n) {
  long i = ((long)blockIdx.x * 256 + threadIdx.x) * 4;
  if (i + 3 < n) {
    float4 v = *(const float4*)(s + i);
    ushort4 o;
    o.x = f2bf(v.x); o.y = f2bf(v.y); o.z = f2bf(v.z); o.w = f2bf(v.w);
    *(ushort4*)(d + i) = o;
  }
}

// ------- batched 2048x2048 transpose + convert (f32 K-major -> bf16 N-major)
struct TransposeBatch {
  const float* src[6];
  u16* dst[6];
};

__global__ __launch_bounds__(256) void transpose2048_batch(TransposeBatch p) {
  const float* __restrict__ W = p.src[blockIdx.z];
  u16* __restrict__ Wt = p.dst[blockIdx.z];
  __shared__ u16 t[64][65];
  int c0 = blockIdx.x * 64, r0 = blockIdx.y * 64;
  int x = threadIdx.x & 63, y = threadIdx.x >> 6;
  for (int yy = y; yy < 64; yy += 4)
    t[yy][x] = f2bf(W[(long)(r0 + yy) * 2048 + c0 + x]);
  __syncthreads();
  for (int yy = y; yy < 64; yy += 4)
    Wt[(long)(c0 + yy) * 2048 + r0 + x] = t[x][yy];
}

// ---------------- GEMM (legacy 128x128): kept for the small KV projections --
// DUAL=1: n in [2048,4096) goes to Yv2/bias2 (two fused output tensors).
template <int OUTF, int DUAL>
__global__ __launch_bounds__(256, 2) void gemm_bias_bt(
    const u16* __restrict__ A, const u16* __restrict__ Bt,
    const float* __restrict__ bias, const float* __restrict__ bias2,
    void* __restrict__ Yv, void* __restrict__ Yv2, int M, int rpb, int bstride,
    int roff) {
  __shared__ u16 smA[128 * 32];
  __shared__ u16 smB[128 * 32];
  const int tid = threadIdx.x;
  const int wave = tid >> 6, lane = tid & 63;
  const int lo = lane & 15, qd = lane >> 4;
  const int m0 = blockIdx.x * 128, n0 = blockIdx.y * 128;
  const int wm = (wave & 1) * 64, wn = (wave >> 1) * 64;

  const u16* aG[2];
  const u16* bG[2];
  u16* aL[2];
  u16* bL[2];
#pragma unroll
  for (int r = 0; r < 2; ++r) {
    int c = (wave * 2 + r) * 64 + lane;  // 16B chunk id, c = row*4 + seg
    int row = c >> 2, seg = c & 3;
    int gr = m0 + row;
    if (gr > M - 1) gr = M - 1;
    long grow = (long)(gr / rpb) * bstride + roff + (gr % rpb);
    aG[r] = A + grow * 2048 + seg * 8;
    bG[r] = Bt + (long)(n0 + row) * 2048 + seg * 8;
    aL[r] = smA + (wave * 2 + r) * 512;  // wave-uniform LDS base
    bL[r] = smB + (wave * 2 + r) * 512;
  }

  f32x4 acc[4][4] = {};
  for (int k0 = 0; k0 < 2048; k0 += 32) {
    GLDS16(aG[0] + k0, aL[0]);
    GLDS16(aG[1] + k0, aL[1]);
    GLDS16(bG[0] + k0, bL[0]);
    GLDS16(bG[1] + k0, bL[1]);
    __syncthreads();
    s8v af[4], bf[4];
#pragma unroll
    for (int i = 0; i < 4; i++)
      af[i] = *(const s8v*)(smA + (wm + i * 16 + lo) * 32 + qd * 8);
#pragma unroll
    for (int i = 0; i < 4; i++)
      bf[i] = *(const s8v*)(smB + (wn + i * 16 + lo) * 32 + qd * 8);
#pragma unroll
    for (int i = 0; i < 4; i++)
#pragma unroll
      for (int j = 0; j < 4; j++) acc[i][j] = MFMA16(af[i], bf[j], acc[i][j]);
    __syncthreads();
  }
#pragma unroll
  for (int j = 0; j < 4; j++) {
    int nf = n0 + wn + j * 16 + lo;
    const float* bp = bias;
    void* yp = Yv;
    int n = nf;
    if (DUAL && nf >= 2048) {
      bp = bias2;
      yp = Yv2;
      n = nf - 2048;
    }
    float bv = bp[n];
#pragma unroll
    for (int i = 0; i < 4; i++) {
      int mb = m0 + wm + i * 16 + qd * 4;
#pragma unroll
      for (int r = 0; r < 4; r++) {
        int m = mb + r;
        if (m < M) {
          float val = acc[i][j][r] + bv;
          if (OUTF)
            ((float*)yp)[(long)m * 2048 + n] = val;
          else
            ((u16*)yp)[(long)m * 2048 + n] = f2bf(val);
        }
      }
    }
  }
}

// ---------------- GEMM 256x256 / BK=64, phase-split K-loop ------------------
// Round 6: ~75us each (inferred), ~915 TF. This round: issue the ENTIRE next
// tile (8 GLDS) in phase 0 instead of half in each phase -> the vmcnt(0)
// drain at tile end sees loads issued a full MFMA phase (~160+ cy) earlier.
template <int OUTF>
__global__ __launch_bounds__(512, 2) void gemm256(
    const u16* __restrict__ A, const u16* __restrict__ Bt,
    const float* __restrict__ bias, void* __restrict__ Yv) {
  __shared__ u16 smA[2][16384];  // [dbuf][256 rows x 64 k] (64KB)
  __shared__ u16 smB[2][16384];  // (64KB)
  const int tid = threadIdx.x;
  const int wave = tid >> 6, lane = tid & 63;
  const int lo = lane & 15, qd = lane >> 4;
  const int m0 = blockIdx.x * 256, n0 = blockIdx.y * 256;
  const int wm = (wave >> 2) * 128, wn = (wave & 3) * 64;
  const int wbase = (tid & ~63);  // wave*64, lane-uniform

  // stage half of tile t (4 of 8 GLDS) into buf b. 2048 chunks of 16B per
  // 256x64 tile; chunk ci = row*8 + c; source col pre-swizzled c^(row&7).
  auto stage_h = [&](int b, int t, int half) {
#pragma unroll
    for (int j = half * 2; j < half * 2 + 2; ++j) {
      int ci = j * 512 + tid;
      int r = ci >> 3, c = ci & 7;
      GLDS16(A + (long)(m0 + r) * 2048 + t * 64 + ((c ^ (r & 7)) << 3),
             &smA[b][(j * 512 + wbase) * 8]);
    }
#pragma unroll
    for (int j = half * 2; j < half * 2 + 2; ++j) {
      int ci = j * 512 + tid;
      int r = ci >> 3, c = ci & 7;
      GLDS16(Bt + (long)(n0 + r) * 2048 + t * 64 + ((c ^ (r & 7)) << 3),
             &smB[b][(j * 512 + wbase) * 8]);
    }
  };
  // fragment readers: row stride 64 elems (8 chunks); swizzled chunk index.
  auto rdA = [&](int b, int ks, int mf) {
    int r = wm + mf * 16 + lo;
    int sc = (ks * 4 + qd) ^ (r & 7);
    return *(const s8v*)(&smA[b][r * 64 + sc * 8]);
  };
  auto rdB = [&](int b, int ks, int nf) {
    int r = wn + nf * 16 + lo;
    int sc = (ks * 4 + qd) ^ (r & 7);
    return *(const s8v*)(&smB[b][r * 64 + sc * 8]);
  };

  f32x4 acc[8][4] = {};
  stage_h(0, 0, 0); stage_h(0, 0, 1);   // tile 0 -> buf 0 (8 loads)
  stage_h(1, 1, 0); stage_h(1, 1, 1);   // tile 1 -> buf 1 (8 loads)
  asm volatile("s_waitcnt vmcnt(8)" ::: "memory");  // tile 0 landed
  __builtin_amdgcn_s_barrier();

  for (int t = 0; t < 32; ++t) {
    const int b = t & 1;
    s8v af[8], bf[4];
    // ---- phase 0 (k-step 0): issue full next-tile prefetch here ----
#pragma unroll
    for (int mf = 0; mf < 8; ++mf) af[mf] = rdA(b, 0, mf);
#pragma unroll
    for (int nf = 0; nf < 4; ++nf) bf[nf] = rdB(b, 0, nf);
    if (t < 31) {
      stage_h(b ^ 1, t + 1, 0);
      stage_h(b ^ 1, t + 1, 1);
    }
    __builtin_amdgcn_s_setprio(1);
#pragma unroll
    for (int mf = 0; mf < 8; ++mf)
#pragma unroll
      for (int nf = 0; nf < 4; ++nf)
        acc[mf][nf] = MFMA16(af[mf], bf[nf], acc[mf][nf]);
    __builtin_amdgcn_s_setprio(0);
    __builtin_amdgcn_s_barrier();  // pacing: waves alternate LDS<->MFMA
    // ---- phase 1 (k-step 1) ----
#pragma unroll
    for (int mf = 0; mf < 8; ++mf) af[mf] = rdA(b, 1, mf);
#pragma unroll
    for (int nf = 0; nf < 4; ++nf) bf[nf] = rdB(b, 1, nf);
    __builtin_amdgcn_s_setprio(1);
#pragma unroll
    for (int mf = 0; mf < 8; ++mf)
#pragma unroll
      for (int nf = 0; nf < 4; ++nf)
        acc[mf][nf] = MFMA16(af[mf], bf[nf], acc[mf][nf]);
    __builtin_amdgcn_s_setprio(0);
    asm volatile("s_waitcnt vmcnt(0)" ::: "memory");  // next tile resident
    __builtin_amdgcn_s_barrier();
  }

  // ---- epilogue: bias + store (f32 rows coalesce to 64B granules) ----
#pragma unroll
  for (int nf = 0; nf < 4; ++nf) {
    int n = n0 + wn + nf * 16 + lo;
    float bv = bias[n];
#pragma unroll
    for (int mf = 0; mf < 8; ++mf) {
      int mb = m0 + wm + mf * 16 + qd * 4;
#pragma unroll
      for (int r = 0; r < 4; ++r) {
        float val = acc[mf][nf][r] + bv;
        if (OUTF)
          ((float*)Yv)[(long)(mb + r) * 2048 + n] = val;
        else
          ((u16*)Yv)[(long)(mb + r) * 2048 + n] = f2bf(val);
      }
    }
  }
}

// ---------------- RMS norm over rows of 2048 (bf16 in place, f32 scale) -----
__global__ __launch_bounds__(256) void rmsnorm_rows(u16* __restrict__ X,
                                                    const float* __restrict__ sc) {
  long row = blockIdx.x;
  u16* xr = X + row * 2048;
  int tid = threadIdx.x;
  s8v v = *(const s8v*)(xr + tid * 8);
  float f[8], ss = 0.f;
#pragma unroll
  for (int j = 0; j < 8; j++) {
    f[j] = bf2f((u16)v[j]);
    ss += f[j] * f[j];
  }
  for (int o = 1; o < 64; o <<= 1) ss += __shfl_xor(ss, o);
  __shared__ float wsum[4];
  if ((tid & 63) == 0) wsum[tid >> 6] = ss;
  __syncthreads();
  float tot = wsum[0] + wsum[1] + wsum[2] + wsum[3];
  float rs = rsqrtf(tot * (1.f / 2048.f) + 1e-6f);
  float4 s0 = *(const float4*)(sc + tid * 8);
  float4 s1 = *(const float4*)(sc + tid * 8 + 4);
  float scv[8] = {s0.x, s0.y, s0.z, s0.w, s1.x, s1.y, s1.z, s1.w};
  s8v o8;
#pragma unroll
  for (int j = 0; j < 8; j++) o8[j] = (short)f2bf(f[j] * rs * scv[j]);
  *(s8v*)(xr + tid * 8) = o8;
}

// ---------------- V repack: V[b][l][h][d] -> VT[b][h][d][l] (zero-pad l) ----
__global__ __launch_bounds__(256) void repack_vt(const u16* __restrict__ V,
                                                 u16* __restrict__ VT, int L,
                                                 int Lpad) {
  int bh = blockIdx.z;  // b*16 + h
  int b = bh >> 4, h = bh & 15;
  int l0 = blockIdx.x * 64, d0 = blockIdx.y * 64;
  __shared__ u16 t[64][65];
  int x = threadIdx.x & 63, y = threadIdx.x >> 6;
  for (int yy = y; yy < 64; yy += 4) {
    int l = l0 + yy;
    u16 val = 0;
    if (l < L) val = V[((long)(b * L + l)) * 2048 + h * 128 + d0 + x];
    t[yy][x] = val;
  }
  __syncthreads();
  for (int yy = y; yy < 64; yy += 4) {
    int d = d0 + yy;
    int l = l0 + x;
    if (l < Lpad) VT[((long)bh * 128 + d) * Lpad + l] = t[x][yy];
  }
}

// ---------------- fused txt+img cross-attention, VALU-dieted ----------------
// Round 6 counters: VALUBusy 33.5 > MfmaUtil 20.9 -> softmax-phase VALU-bound.
// This round: (a) compile-time mask specialization -- txt L=512 is exactly 16
// tiles (never masked); img masks ONLY its last tile; (b) denominator via
// ones-MFMA: P (bf16, in LDS, masked keys already 0) x ones-B accumulates the
// complete row-sum in oacc layout -> kills 16 lsum adds/step + the final
// 16-lane shuffle reduce. Denominator now sums bf16 P (was f32) -- same P the
// PV numerator uses, so errors track; watch absmax.
template <int LT, int LPT, int NTT, int LI, int LPI, int NTI>
__global__ __launch_bounds__(256, 2) void cross_attn_fused(
    const u16* __restrict__ Q, const u16* __restrict__ Kt,
    const u16* __restrict__ VTt, const u16* __restrict__ Ki,
    const u16* __restrict__ VTi, u16* __restrict__ O) {
  const int tid = threadIdx.x, wave = tid >> 6, lane = tid & 63;
  const int lo = lane & 15, qd = lane >> 4;
  const int id = blockIdx.x;                 // 1024 blocks
  const int xp = id & 7, xr = id >> 3;       // xp: XCD slot, xr in [0,128)
  const int t = xr & 31;                     // q-tile
  const int f = xp * 4 + (xr >> 5);          // family in [0,32)
  const int h = f & 15, b = f >> 4;
  const int q0 = t * 128 + wave * 32;

  __shared__ u16 smem[38912];                // 76 KB
  u16* lk = smem;                            // 2 bufs x 4096 u16 (K tile)
  u16* lv = smem + 8192;                     // 2 bufs x 4096 u16 (V tile)
  u16* pls = smem + 16384;                   // [wave][1280] P slice (single)
  u16* oTs = smem + 21504;                   // [wave][4352] txt result stage

  const u16* Kbt = Kt + ((long)b * LT) * 2048 + h * 128;
  const u16* VTbt = VTt + ((long)(b * 16 + h)) * 128 * LPT;
  const u16* Kbi = Ki + ((long)b * LI) * 2048 + h * 128;
  const u16* VTbi = VTi + ((long)(b * 16 + h)) * 128 * LPI;

  auto stage = [&](int pb, int gt) {
    const u16* Kb;
    const u16* VTb;
    int kt, L, LPAD;
    if (gt < NTT) {
      Kb = Kbt; VTb = VTbt; kt = gt; L = LT; LPAD = LPT;
    } else {
      Kb = Kbi; VTb = VTbi; kt = gt - NTT; L = LI; LPAD = LPI;
    }
#pragma unroll
    for (int j = 0; j < 2; ++j) {
      int ci = (wave * 2 + j) * 64 + lane;   // 16B chunk id in 32x128 K tile
      int r = ci >> 4, c = ci & 15;
      int key = kt * 32 + r;
      if (key > L - 1) key = L - 1;
      const u16* src = Kb + (long)key * 2048 + (c ^ (r & 7)) * 8;
      GLDS16(src, &lk[pb * 4096 + (wave * 2 + j) * 512]);
    }
#pragma unroll
    for (int j = 0; j < 2; ++j) {
      int ci = (wave * 2 + j) * 64 + lane;   // 16B chunk id in 128x32 V tile
      int d = ci >> 2, c = ci & 3;
      const u16* src = VTb + (long)d * LPAD + kt * 32 + (c ^ ((d >> 1) & 3)) * 8;
      GLDS16(src, &lv[pb * 4096 + (wave * 2 + j) * 512]);
    }
  };

  s8v aq[2][4];
#pragma unroll
  for (int qf = 0; qf < 2; ++qf) {
    const u16* qp =
        Q + ((long)(b * 4096 + q0 + qf * 16 + lo)) * 2048 + h * 128 + qd * 8;
#pragma unroll
    for (int ds = 0; ds < 4; ++ds) aq[qf][ds] = *(const s8v*)(qp + ds * 32);
  }

  const float SC = 0.08838834764831845f;  // 1/sqrt(128)
  const int vsw = (lo >> 1) & 3;          // V read swizzle
  s8v vones;
#pragma unroll
  for (int j = 0; j < 8; ++j) vones[j] = (short)0x3F80;  // bf16 1.0

  // one K-tile step. lones accumulates the P row-sums (denominator) via an
  // extra ones-B MFMA per qf; mask work only when MaskTag<true>.
  auto tile_step = [&](int pb, int ktile, int Lcur, f32x4 (&oacc)[2][8],
                       f32x4 (&lones)[2], auto mt) {
    constexpr bool DOMASK = decltype(mt)::do_mask;
    s8v bk[2][4];
#pragma unroll
    for (int nf = 0; nf < 2; ++nf) {
      int r = nf * 16 + lo;
#pragma unroll
      for (int ds = 0; ds < 4; ++ds) {
        int cp = (ds * 4 + qd) ^ (r & 7);
        bk[nf][ds] = *(const s8v*)(&lk[pb * 4096 + r * 128 + cp * 8]);
      }
    }
    f32x4 sacc[2][2] = {};
    __builtin_amdgcn_s_setprio(1);
#pragma unroll
    for (int qf = 0; qf < 2; ++qf)
#pragma unroll
      for (int nf = 0; nf < 2; ++nf)
#pragma unroll
        for (int ds = 0; ds < 4; ++ds)
          sacc[qf][nf] = MFMA16(aq[qf][ds], bk[nf][ds], sacc[qf][nf]);
    __builtin_amdgcn_s_setprio(0);
    u16* pw = pls + wave * 1280;
#pragma unroll
    for (int qf = 0; qf < 2; ++qf)
#pragma unroll
      for (int nf = 0; nf < 2; ++nf) {
        bool msk = false;
        if constexpr (DOMASK) {
          int key = ktile * 32 + nf * 16 + lo;
          msk = key >= Lcur;
        }
#pragma unroll
        for (int r = 0; r < 4; ++r) {
          float s = fminf(fmaf(sacc[qf][nf][r], SC, -12.f), 50.f);
          float p = __expf(s);
          if constexpr (DOMASK) p = msk ? 0.f : p;
          pw[(qf * 16 + qd * 4 + r) * 40 + nf * 16 + lo] = f2bf(p);
        }
      }
    s8v pa[2];
#pragma unroll
    for (int qf = 0; qf < 2; ++qf)
      pa[qf] = *(const s8v*)(pw + (qf * 16 + lo) * 40 + qd * 8);
    __builtin_amdgcn_s_setprio(1);
#pragma unroll
    for (int df = 0; df < 8; ++df) {
      int d = df * 16 + lo;
      s8v bv = *(const s8v*)(&lv[pb * 4096 + d * 32 + (qd ^ vsw) * 8]);
      oacc[0][df] = MFMA16(pa[0], bv, oacc[0][df]);
      oacc[1][df] = MFMA16(pa[1], bv, oacc[1][df]);
    }
    lones[0] = MFMA16(pa[0], vones, lones[0]);
    lones[1] = MFMA16(pa[1], vones, lones[1]);
    __builtin_amdgcn_s_setprio(0);
  };

  stage(0, 0);
  __syncthreads();  // tile 0 resident

  u16* ep = oTs + wave * 4352;

  // ---- txt pass: L=512 = exactly 16 tiles, NEVER masked ----
  {
    f32x4 oT[2][8] = {};
    f32x4 lonesT[2] = {};
#pragma unroll 2
    for (int kt = 0; kt < NTT; ++kt) {
      const int pb = kt & 1;
      stage(pb ^ 1, kt + 1);  // kt==NTT-1 stages img tile 0
      tile_step(pb, kt, LT, oT, lonesT, MaskTag<false>{});
      __syncthreads();
    }
    // normalize (denominator = lones, already per-q complete) and park in LDS.
    float invT[2][4];
#pragma unroll
    for (int qf = 0; qf < 2; ++qf)
#pragma unroll
      for (int r = 0; r < 4; ++r) invT[qf][r] = 1.f / lonesT[qf][r];
#pragma unroll
    for (int qf = 0; qf < 2; ++qf)
#pragma unroll
      for (int df = 0; df < 8; ++df)
#pragma unroll
        for (int r = 0; r < 4; ++r)
          ep[(qf * 16 + qd * 4 + r) * 136 + df * 16 + lo] =
              f2bf(oT[qf][df][r] * invT[qf][r]);
  }

  // ---- img pass: tiles 0..NTI-2 unmasked (keys < 256 < L), last masked ----
  f32x4 oI[2][8] = {};
  f32x4 lonesI[2] = {};
#pragma unroll 2
  for (int kt = 0; kt < NTI - 1; ++kt) {
    const int pb = kt & 1;
    stage(pb ^ 1, NTT + kt + 1);
    tile_step(pb, kt, LI, oI, lonesI, MaskTag<false>{});
    __syncthreads();
  }
  tile_step((NTI - 1) & 1, NTI - 1, LI, oI, lonesI, MaskTag<true>{});

  // ---- img denominator, combine with parked txt result, coalesced write ----
  float invI[2][4];
#pragma unroll
  for (int qf = 0; qf < 2; ++qf)
#pragma unroll
    for (int r = 0; r < 4; ++r) invI[qf][r] = 1.f / lonesI[qf][r];
#pragma unroll
  for (int qf = 0; qf < 2; ++qf)
#pragma unroll
    for (int df = 0; df < 8; ++df)
#pragma unroll
      for (int r = 0; r < 4; ++r) {
        int idx = (qf * 16 + qd * 4 + r) * 136 + df * 16 + lo;
        float val = bf2f(ep[idx]) + oI[qf][df][r] * invI[qf][r];
        ep[idx] = f2bf(val);
      }
  const int row = lane >> 1, half = lane & 1;
  const u16* srcp = ep + row * 136 + half * 64;
  u16* gdst = O + ((long)(b * 4096 + q0 + row)) * 2048 + h * 128 + half * 64;
#pragma unroll
  for (int c = 0; c < 8; ++c) *(s8v*)(gdst + c * 8) = *(const s8v*)(srcp + c * 8);
}

extern "C" void kernel_launch(void* const* d_in, const int* in_sizes, int n_in,
                              void* d_out, int out_size, void* d_ws,
                              size_t ws_size, hipStream_t stream) {
  const float* x = (const float*)d_in[0];
  const float* ctx = (const float*)d_in[1];
  const float* q_w = (const float*)d_in[2];
  const float* q_b = (const float*)d_in[3];
  const float* k_w = (const float*)d_in[4];
  const float* k_b = (const float*)d_in[5];
  const float* v_w = (const float*)d_in[6];
  const float* v_b = (const float*)d_in[7];
  const float* ki_w = (const float*)d_in[8];
  const float* ki_b = (const float*)d_in[9];
  const float* vi_w = (const float*)d_in[10];
  const float* vi_b = (const float*)d_in[11];
  const float* o_w = (const float*)d_in[12];
  const float* o_b = (const float*)d_in[13];
  const float* nq_s = (const float*)d_in[14];
  const float* nkt_s = (const float*)d_in[15];
  const float* nki_s = (const float*)d_in[16];
  float* out = (float*)d_out;
  u16* ws = (u16*)d_ws;

  // workspace layout (u16 elements); total ~103 MB
  u16* w0 = ws;                        //  4,194,304  (q_w^T)
  u16* w1 = ws + 4194304L;             //  4,194,304  (o_w^T)
  u16* q = ws + 8388608L;              // 16,777,216
  u16* attn = ws + 25165824L;          // 16,777,216
  u16* xb = attn;                      // alias (x bf16; dead before attn written)
  u16* vtxt = attn;                    // alias, 2,097,152 (dead before xb written)
  u16* vimg = attn + 2097152L;         // alias, 1,052,672
  u16* ktxt = ws + 41943040L;          //  2,097,152
  u16* kimg = ws + 44040192L;          //  1,052,672
  u16* vttxt = ws + 45092864L;         //  2,097,152 (32 x 128 x 512)
  u16* vtimg = ws + 47190016L;         //  1,179,648 (32 x 128 x 288)
  u16* ctxb = ws + 48369664L;          //  3,149,824

  dim3 tb(256);

  // Phase 0: context to bf16 + ALL weight transposes in one launch.
  cvt_f32_bf16<<<3076, tb, 0, stream>>>(ctx, ctxb, 3149824L);
  TransposeBatch tp;
  tp.src[0] = q_w;  tp.dst[0] = w0;
  tp.src[1] = o_w;  tp.dst[1] = w1;
  tp.src[2] = k_w;  tp.dst[2] = q;              // dual pair base (txt)
  tp.src[3] = v_w;  tp.dst[3] = q + 4194304L;
  tp.src[4] = ki_w; tp.dst[4] = q + 8388608L;   // dual pair base (img)
  tp.src[5] = vi_w; tp.dst[5] = q + 12582912L;
  transpose2048_batch<<<dim3(32, 32, 6), tb, 0, stream>>>(tp);

  // Phase 1: K|V projections (weights live in q region; q not written yet).
  gemm_bias_bt<0, 1><<<dim3(8, 32), tb, 0, stream>>>(
      ctxb, q, k_b, v_b, ktxt, vtxt, 1024, 512, 769, 257);
  gemm_bias_bt<0, 1><<<dim3(5, 32), tb, 0, stream>>>(
      ctxb, q + 8388608L, ki_b, vi_b, kimg, vimg, 514, 257, 769, 0);

  rmsnorm_rows<<<1024, tb, 0, stream>>>(ktxt, nkt_s);
  rmsnorm_rows<<<514, tb, 0, stream>>>(kimg, nki_s);
  repack_vt<<<dim3(8, 2, 32), tb, 0, stream>>>(vtxt, vttxt, 512, 512);
  repack_vt<<<dim3(5, 2, 32), tb, 0, stream>>>(vimg, vtimg, 257, 288);

  // Phase 2: x to bf16 (overwrites the now-repacked vtxt/vimg aliases),
  // then Q projection on the 256^2 phase-split kernel.
  cvt_f32_bf16<<<16384, tb, 0, stream>>>(x, xb, 16777216L);
  gemm256<0><<<dim3(32, 8), dim3(512), 0, stream>>>(xb, w0, q_b, q);
  rmsnorm_rows<<<8192, tb, 0, stream>>>(q, nq_s);

  // Phase 3: fused attention (txt + img in one dispatch, single attn write).
  cross_attn_fused<512, 512, 16, 257, 288, 9><<<1024, tb, 0, stream>>>(
      q, ktxt, vttxt, kimg, vtimg, attn);

  // Phase 4: output projection on the 256^2 phase-split kernel.
  gemm256<1><<<dim3(32, 8), dim3(512), 0, stream>>>(attn, w1, o_b, out);
}